// Round 1
// baseline (10959.686 us; speedup 1.0000x reference)
//
#include <hip/hip_runtime.h>

// Problem constants (fixed by the reference)
#define DD   300     // emb dim
#define DD2  600     // 2*D
#define GG   4000    // graphs
#define LL   5       // layers
#define TN   8       // nodes per MLP block
#define BN_EPS 1e-5f

// ---------------------------------------------------------------- counts
__global__ __launch_bounds__(256) void k_counts(const int* __restrict__ batch,
                                                float* __restrict__ counts, int N) {
    int i = blockIdx.x * 256 + threadIdx.x;
    if (i < N) atomicAdd(&counts[batch[i]], 1.0f);
}

// ---------------------------------------------------------------- h init
__global__ __launch_bounds__(256) void k_init_h(const int* __restrict__ xa, const int* __restrict__ xc,
                                                const float* __restrict__ emb1, const float* __restrict__ emb2,
                                                const float* __restrict__ vne,
                                                float* __restrict__ h, int N) {
    int n = blockIdx.x;
    if (n >= N) return;
    int a = xa[n], c = xc[n];
    for (int d = threadIdx.x; d < DD; d += 256)
        h[(size_t)n * DD + d] = emb1[(size_t)a * DD + d] + emb2[(size_t)c * DD + d] + vne[d];
}

__global__ __launch_bounds__(256) void k_init_vn(const float* __restrict__ vne, float* __restrict__ vnh) {
    int g = blockIdx.x;
    for (int d = threadIdx.x; d < DD; d += 256) vnh[(size_t)g * DD + d] = vne[d];
}

// ------------------------------------------- aggr = h + selfloop edge emb
__global__ __launch_bounds__(256) void k_self(const float* __restrict__ h, float* __restrict__ aggr,
                                              const float* __restrict__ e1s, const float* __restrict__ e2s,
                                              int N) {
    int n = blockIdx.x;
    if (n >= N) return;
    for (int d = threadIdx.x; d < DD; d += 256)
        aggr[(size_t)n * DD + d] = h[(size_t)n * DD + d] + e1s[d] + e2s[d];
}

// ------------------------------------------- scatter messages (atomics)
__global__ __launch_bounds__(256) void k_scatter(const float* __restrict__ h, float* __restrict__ aggr,
                                                 const int* __restrict__ src, const int* __restrict__ dst,
                                                 const int* __restrict__ ety, const int* __restrict__ edir,
                                                 const float* __restrict__ e1, const float* __restrict__ e2,
                                                 int E) {
    int e = blockIdx.x;
    if (e >= E) return;
    int s = src[e], td = dst[e];
    const float* r1 = e1 + (size_t)ety[e] * DD;
    const float* r2 = e2 + (size_t)edir[e] * DD;
    const float* hs = h + (size_t)s * DD;
    float* ad = aggr + (size_t)td * DD;
    for (int d = threadIdx.x; d < DD; d += 256)
        atomicAdd(&ad[d], hs[d] + r1[d] + r2[d]);
}

// ------------------------------------------- fused MLP + BN (+ReLU)
// z = BN( relu(aggr @ W1 + b1) @ W2 + b2 ) [; relu]
// One block handles TN node rows. GEMM1: 600 cols -> 3 col-slots/thread.
// GEMM2: 300 cols -> 2 col-slots/thread. Register tile over TN nodes.
__global__ __launch_bounds__(256) void k_mlp(const float* __restrict__ aggr, float* __restrict__ hout,
                                             const float* __restrict__ w1, const float* __restrict__ b1,
                                             const float* __restrict__ w2, const float* __restrict__ b2,
                                             const float* __restrict__ bng, const float* __restrict__ bnb,
                                             const float* __restrict__ bnm, const float* __restrict__ bnv,
                                             int relu_out, int N) {
    __shared__ float sA[TN * DD];    // 9.6 KB  (rows 16B-aligned: 300*4 = 1200 % 16 == 0)
    __shared__ float sH[TN * DD2];   // 19.2 KB (600*4 = 2400 % 16 == 0)
    const int t  = threadIdx.x;
    const int n0 = blockIdx.x * TN;

    // stage aggr tile: TN*DD contiguous floats
    const size_t lim = (size_t)N * DD - 1;
    for (int i = t; i < TN * DD; i += 256) {
        size_t gi = (size_t)n0 * DD + i;
        sA[i] = aggr[gi > lim ? lim : gi];
    }
    __syncthreads();

    const int j0 = t, j1 = t + 256, j2 = t + 512;
    const bool h2 = (j2 < DD2);

    // ---- GEMM1: hidden = relu(aggr @ W1 + b1) ----
    float acc0[TN], acc1[TN], acc2[TN];
#pragma unroll
    for (int n = 0; n < TN; n++) { acc0[n] = 0.f; acc1[n] = 0.f; acc2[n] = 0.f; }
    for (int k = 0; k < DD; k += 4) {
        float4 a[TN];
#pragma unroll
        for (int n = 0; n < TN; n++) a[n] = *(const float4*)&sA[n * DD + k];
#pragma unroll
        for (int kk = 0; kk < 4; kk++) {
            const float* wr = w1 + (size_t)(k + kk) * DD2;
            float wa = wr[j0], wb = wr[j1], wc = h2 ? wr[j2] : 0.f;
#pragma unroll
            for (int n = 0; n < TN; n++) {
                float av = (kk == 0) ? a[n].x : (kk == 1) ? a[n].y : (kk == 2) ? a[n].z : a[n].w;
                acc0[n] = fmaf(av, wa, acc0[n]);
                acc1[n] = fmaf(av, wb, acc1[n]);
                acc2[n] = fmaf(av, wc, acc2[n]);
            }
        }
    }
    {
        float ba = b1[j0], bb = b1[j1], bc = h2 ? b1[j2] : 0.f;
#pragma unroll
        for (int n = 0; n < TN; n++) {
            sH[n * DD2 + j0] = fmaxf(acc0[n] + ba, 0.f);
            sH[n * DD2 + j1] = fmaxf(acc1[n] + bb, 0.f);
            if (h2) sH[n * DD2 + j2] = fmaxf(acc2[n] + bc, 0.f);
        }
    }
    __syncthreads();

    // ---- GEMM2: z = hidden @ W2 + b2 ----
    const bool g1 = (j1 < DD);
    float z0[TN], z1[TN];
#pragma unroll
    for (int n = 0; n < TN; n++) { z0[n] = 0.f; z1[n] = 0.f; }
    for (int k = 0; k < DD2; k += 4) {
        float4 hh[TN];
#pragma unroll
        for (int n = 0; n < TN; n++) hh[n] = *(const float4*)&sH[n * DD2 + k];
#pragma unroll
        for (int kk = 0; kk < 4; kk++) {
            const float* wr = w2 + (size_t)(k + kk) * DD;
            float wa = wr[j0], wb = g1 ? wr[j1] : 0.f;
#pragma unroll
            for (int n = 0; n < TN; n++) {
                float hv = (kk == 0) ? hh[n].x : (kk == 1) ? hh[n].y : (kk == 2) ? hh[n].z : hh[n].w;
                z0[n] = fmaf(hv, wa, z0[n]);
                z1[n] = fmaf(hv, wb, z1[n]);
            }
        }
    }
    // ---- epilogue: bias + BN (+ReLU) ----
    {
        float sc = bng[j0] * rsqrtf(bnv[j0] + BN_EPS);
        float mB = bnm[j0], bB = bnb[j0], bz = b2[j0];
#pragma unroll
        for (int n = 0; n < TN; n++) {
            int row = n0 + n;
            if (row < N) {
                float z = (z0[n] + bz - mB) * sc + bB;
                if (relu_out) z = fmaxf(z, 0.f);
                hout[(size_t)row * DD + j0] = z;
            }
        }
    }
    if (g1) {
        float sc = bng[j1] * rsqrtf(bnv[j1] + BN_EPS);
        float mB = bnm[j1], bB = bnb[j1], bz = b2[j1];
#pragma unroll
        for (int n = 0; n < TN; n++) {
            int row = n0 + n;
            if (row < N) {
                float z = (z1[n] + bz - mB) * sc + bB;
                if (relu_out) z = fmaxf(z, 0.f);
                hout[(size_t)row * DD + j1] = z;
            }
        }
    }
}

// ------------------------------------------- mean-pool scatter
__global__ __launch_bounds__(256) void k_pool(const float* __restrict__ z, const int* __restrict__ batch,
                                              float* __restrict__ pooled, int N) {
    int n = blockIdx.x;
    if (n >= N) return;
    int g = batch[n];
    const float* zr = z + (size_t)n * DD;
    float* pr = pooled + (size_t)g * DD;
    for (int d = threadIdx.x; d < DD; d += 256) atomicAdd(&pr[d], zr[d]);
}

// ------------------------------------------- virtual-node MLP (block/graph)
__global__ __launch_bounds__(256) void k_vn(const float* __restrict__ pooled, const float* __restrict__ counts,
                                            float* __restrict__ vnh,
                                            const float* __restrict__ w1, const float* __restrict__ b1,
                                            const float* __restrict__ lng, const float* __restrict__ lnb,
                                            const float* __restrict__ w2, const float* __restrict__ b2) {
    __shared__ float sV[DD];
    __shared__ float sT[DD];
    __shared__ float rs[4], rq[4];
    __shared__ float s_mu, s_rstd;
    int g = blockIdx.x, t = threadIdx.x;
    float inv = 1.0f / fmaxf(counts[g], 1.0f);
    for (int i = t; i < DD; i += 256)
        sV[i] = pooled[(size_t)g * DD + i] * inv + vnh[(size_t)g * DD + i];
    __syncthreads();

    const int j0 = t, j1 = t + 256;
    const bool g1 = (j1 < DD);
    // t = vn_new @ W1 + b1
    float a0 = 0.f, a1 = 0.f;
    for (int k = 0; k < DD; k++) {
        float v = sV[k];
        const float* wr = w1 + (size_t)k * DD;
        a0 = fmaf(v, wr[j0], a0);
        a1 = fmaf(v, g1 ? wr[j1] : 0.f, a1);
    }
    float t0 = a0 + b1[j0];
    float t1 = g1 ? (a1 + b1[j1]) : 0.f;
    sT[j0] = t0;
    if (g1) sT[j1] = t1;
    __syncthreads();

    // LayerNorm stats over DD
    float ps = 0.f, pq = 0.f;
    for (int i = t; i < DD; i += 256) { float x = sT[i]; ps += x; pq += x * x; }
    for (int off = 32; off >= 1; off >>= 1) { ps += __shfl_down(ps, off, 64); pq += __shfl_down(pq, off, 64); }
    int wid = t >> 6, lane = t & 63;
    if (lane == 0) { rs[wid] = ps; rq[wid] = pq; }
    __syncthreads();
    if (t == 0) {
        float S = rs[0] + rs[1] + rs[2] + rs[3];
        float Q = rq[0] + rq[1] + rq[2] + rq[3];
        float mu = S / DD;
        float var = Q / DD - mu * mu;
        s_mu = mu;
        s_rstd = rsqrtf(var + BN_EPS);
    }
    __syncthreads();
    float mu = s_mu, rstd = s_rstd;
    float r0 = fmaxf((t0 - mu) * rstd * lng[j0] + lnb[j0], 0.f);
    float r1 = g1 ? fmaxf((t1 - mu) * rstd * lng[j1] + lnb[j1], 0.f) : 0.f;
    sT[j0] = r0;           // safe: all reads of old sT completed before the rs/rq barrier
    if (g1) sT[j1] = r1;
    __syncthreads();

    // vn_h = relu(t) @ W2 + b2
    float o0 = 0.f, o1 = 0.f;
    for (int k = 0; k < DD; k++) {
        float v = sT[k];
        const float* wr = w2 + (size_t)k * DD;
        o0 = fmaf(v, wr[j0], o0);
        o1 = fmaf(v, g1 ? wr[j1] : 0.f, o1);
    }
    vnh[(size_t)g * DD + j0] = o0 + b2[j0];
    if (g1) vnh[(size_t)g * DD + j1] = o1 + b2[j1];
}

// ------------------------------------------- z += vn_h[batch]
__global__ __launch_bounds__(256) void k_vnadd(float* __restrict__ h, const int* __restrict__ batch,
                                               const float* __restrict__ vnh, int N) {
    int n = blockIdx.x;
    if (n >= N) return;
    int g = batch[n];
    float* hr = h + (size_t)n * DD;
    const float* vr = vnh + (size_t)g * DD;
    for (int d = threadIdx.x; d < DD; d += 256) hr[d] += vr[d];
}

extern "C" void kernel_launch(void* const* d_in, const int* in_sizes, int n_in,
                              void* d_out, int out_size, void* d_ws, size_t ws_size,
                              hipStream_t stream) {
    const int*   x_atom = (const int*)d_in[0];
    const int*   x_chir = (const int*)d_in[1];
    const int*   src    = (const int*)d_in[2];
    const int*   dst    = (const int*)d_in[3];
    const int*   ety    = (const int*)d_in[4];
    const int*   edir   = (const int*)d_in[5];
    const int*   batch  = (const int*)d_in[6];
    const float* emb1   = (const float*)d_in[7];
    const float* emb2   = (const float*)d_in[8];
    const float* e1     = (const float*)d_in[9];
    const float* e2     = (const float*)d_in[10];
    const float* w1     = (const float*)d_in[11];
    const float* b1     = (const float*)d_in[12];
    const float* w2     = (const float*)d_in[13];
    const float* b2     = (const float*)d_in[14];
    const float* bng    = (const float*)d_in[15];
    const float* bnb    = (const float*)d_in[16];
    const float* bnm    = (const float*)d_in[17];
    const float* bnv    = (const float*)d_in[18];
    const float* vne    = (const float*)d_in[19];
    const float* vw1    = (const float*)d_in[20];
    const float* vb1    = (const float*)d_in[21];
    const float* lng    = (const float*)d_in[22];
    const float* lnb    = (const float*)d_in[23];
    const float* vw2    = (const float*)d_in[24];
    const float* vb2    = (const float*)d_in[25];

    const int N = in_sizes[0];
    const int E = in_sizes[2];

    float* h      = (float*)d_out;                 // [N, D] — doubles as z buffer
    float* aggr   = (float*)d_ws;                  // [N, D]
    float* pooled = aggr + (size_t)N * DD;         // [G, D]
    float* vnh    = pooled + (size_t)GG * DD;      // [G, D]
    float* counts = vnh + (size_t)GG * DD;         // [G]

    hipMemsetAsync(counts, 0, GG * sizeof(float), stream);
    k_counts<<<(N + 255) / 256, 256, 0, stream>>>(batch, counts, N);
    k_init_h<<<N, 256, 0, stream>>>(x_atom, x_chir, emb1, emb2, vne, h, N);
    k_init_vn<<<GG, 256, 0, stream>>>(vne, vnh);

    for (int l = 0; l < LL; l++) {
        k_self<<<N, 256, 0, stream>>>(h, aggr,
                                      e1 + ((size_t)l * 6 + 4) * DD,
                                      e2 + ((size_t)l * 3 + 0) * DD, N);
        k_scatter<<<E, 256, 0, stream>>>(h, aggr, src, dst, ety, edir,
                                         e1 + (size_t)l * 6 * DD,
                                         e2 + (size_t)l * 3 * DD, E);
        k_mlp<<<(N + TN - 1) / TN, 256, 0, stream>>>(aggr, h,
                                                     w1 + (size_t)l * DD * DD2, b1 + (size_t)l * DD2,
                                                     w2 + (size_t)l * DD2 * DD, b2 + (size_t)l * DD,
                                                     bng + (size_t)l * DD, bnb + (size_t)l * DD,
                                                     bnm + (size_t)l * DD, bnv + (size_t)l * DD,
                                                     (l < LL - 1) ? 1 : 0, N);
        if (l < LL - 1) {
            hipMemsetAsync(pooled, 0, (size_t)GG * DD * sizeof(float), stream);
            k_pool<<<N, 256, 0, stream>>>(h, batch, pooled, N);
            k_vn<<<GG, 256, 0, stream>>>(pooled, counts, vnh,
                                         vw1 + (size_t)l * DD * DD, vb1 + (size_t)l * DD,
                                         lng + (size_t)l * DD, lnb + (size_t)l * DD,
                                         vw2 + (size_t)l * DD * DD, vb2 + (size_t)l * DD);
            k_vnadd<<<N, 256, 0, stream>>>(h, batch, vnh, N);
        }
    }
}

// Round 2
// 4564.337 us; speedup vs baseline: 2.4012x; 2.4012x over previous
//
#include <hip/hip_runtime.h>

// Problem constants (fixed by the reference)
#define DD   300     // emb dim
#define DD2  600     // 2*D
#define GG   4000    // graphs
#define LL   5       // layers
#define BN_EPS 1e-5f

typedef float f32x4  __attribute__((ext_vector_type(4)));
typedef short bf16x8 __attribute__((ext_vector_type(8)));

__device__ __forceinline__ unsigned short f2bf(float f) {
    unsigned int x = __float_as_uint(f);
    unsigned int r = (x + 0x7FFFu + ((x >> 16) & 1u)) >> 16;   // RTNE
    return (unsigned short)r;
}

// ---------------------------------------------------------------- counts
__global__ __launch_bounds__(256) void k_counts(const int* __restrict__ batch,
                                                float* __restrict__ counts, int N) {
    int i = blockIdx.x * 256 + threadIdx.x;
    if (i < N) atomicAdd(&counts[batch[i]], 1.0f);
}

// ---------------------------------------------------------------- h init
__global__ __launch_bounds__(256) void k_init_h(const int* __restrict__ xa, const int* __restrict__ xc,
                                                const float* __restrict__ emb1, const float* __restrict__ emb2,
                                                const float* __restrict__ vne,
                                                float* __restrict__ h, int N) {
    int n = blockIdx.x;
    if (n >= N) return;
    int a = xa[n], c = xc[n];
    for (int d = threadIdx.x; d < DD; d += 256)
        h[(size_t)n * DD + d] = emb1[(size_t)a * DD + d] + emb2[(size_t)c * DD + d] + vne[d];
}

__global__ __launch_bounds__(256) void k_init_vn(const float* __restrict__ vne, float* __restrict__ vnh) {
    int g = blockIdx.x;
    for (int d = threadIdx.x; d < DD; d += 256) vnh[(size_t)g * DD + d] = vne[d];
}

// ------------------------------------------- aggr = h + selfloop edge emb
__global__ __launch_bounds__(256) void k_self(const float* __restrict__ h, float* __restrict__ aggr,
                                              const float* __restrict__ e1s, const float* __restrict__ e2s,
                                              int N) {
    int n = blockIdx.x;
    if (n >= N) return;
    for (int d = threadIdx.x; d < DD; d += 256)
        aggr[(size_t)n * DD + d] = h[(size_t)n * DD + d] + e1s[d] + e2s[d];
}

// ------------------------------------------- scatter messages (atomics)
__global__ __launch_bounds__(256) void k_scatter(const float* __restrict__ h, float* __restrict__ aggr,
                                                 const int* __restrict__ src, const int* __restrict__ dst,
                                                 const int* __restrict__ ety, const int* __restrict__ edir,
                                                 const float* __restrict__ e1, const float* __restrict__ e2,
                                                 int E) {
    int e = blockIdx.x;
    if (e >= E) return;
    int s = src[e], td = dst[e];
    const float* r1 = e1 + (size_t)ety[e] * DD;
    const float* r2 = e2 + (size_t)edir[e] * DD;
    const float* hs = h + (size_t)s * DD;
    float* ad = aggr + (size_t)td * DD;
    for (int d = threadIdx.x; d < DD; d += 256)
        atomicAdd(&ad[d], hs[d] + r1[d] + r2[d]);
}

// ------------------------------------------- weight transpose+pad -> bf16
// wt[l][n][k] = bf16(w[l][k][n]), zero pad to [NP][KP]
__global__ __launch_bounds__(256) void k_convw(const float* __restrict__ w, short* __restrict__ wt,
                                               int K, int Nn, int KP, int NP) {
    int n = blockIdx.x;          // 0..NP-1
    int l = blockIdx.y;
    const float* wl = w + (size_t)l * K * Nn;
    short* wtl = wt + (size_t)l * NP * KP;
    for (int k = threadIdx.x; k < KP; k += 256) {
        float v = (k < K && n < Nn) ? wl[(size_t)k * Nn + n] : 0.f;
        wtl[(size_t)n * KP + k] = (short)f2bf(v);
    }
}

__global__ __launch_bounds__(256) void k_padb(const float* __restrict__ b, float* __restrict__ bp) {
    int l = blockIdx.y;
    int n = blockIdx.x * 256 + threadIdx.x;
    if (n < 640) bp[(size_t)l * 640 + n] = (n < DD2) ? b[(size_t)l * DD2 + n] : 0.f;
}

// ------------------------------------------- GEMM1 (MFMA bf16)
// hidden[m][n] = relu(aggr[m][:300] @ W1 + b1)  for m < Npad, n < 640
// block tile: M=64 (wave w owns rows w*16..), N=160 (10 n-tiles), BK=32, dbuf LDS
__global__ __launch_bounds__(256) void k_gemm1(const float* __restrict__ aggr,
                                               const short* __restrict__ w1t,   // [640][320]
                                               const float* __restrict__ b1p,   // [640]
                                               unsigned short* __restrict__ hidden, // [Npad][640]
                                               int N) {
    __shared__ short sA[2][64][40];    // pad 32->40 to break bank aliasing
    __shared__ short sB[2][160][40];
    const int t  = threadIdx.x;
    const int m0 = blockIdx.x * 64;
    const int n0 = blockIdx.y * 160;

    const int ar = t >> 2, aq = (t & 3) << 3;     // A staging: row, k-offset
    const int gm = m0 + ar;

    // ---- stage ks=0 ----
    {
        float av[8];
        if (gm < N) {
            float4 p0 = *(const float4*)(aggr + (size_t)gm * DD + aq);
            float4 p1 = *(const float4*)(aggr + (size_t)gm * DD + aq + 4);
            av[0]=p0.x; av[1]=p0.y; av[2]=p0.z; av[3]=p0.w;
            av[4]=p1.x; av[5]=p1.y; av[6]=p1.z; av[7]=p1.w;
        } else {
#pragma unroll
            for (int j = 0; j < 8; j++) av[j] = 0.f;
        }
        bf16x8 v;
#pragma unroll
        for (int j = 0; j < 8; j++) v[j] = (short)f2bf(av[j]);
        *(bf16x8*)&sA[0][ar][aq] = v;
#pragma unroll
        for (int i = 0; i < 3; i++) {
            int c = t + (i << 8);
            if (c < 640) {
                int br = c >> 2, bq = (c & 3) << 3;
                *(float4*)&sB[0][br][bq] = *(const float4*)(w1t + (size_t)(n0 + br) * 320 + bq);
            }
        }
    }
    __syncthreads();

    const int lane = t & 63;
    const int w    = t >> 6;
    const int mrow = (w << 4) + (lane & 15);
    const int kb   = (lane >> 4) << 3;
    const int col  = lane & 15;
    const int rq   = (lane >> 4) << 2;

    f32x4 acc[10];
#pragma unroll
    for (int nt = 0; nt < 10; nt++) acc[nt] = (f32x4){0.f, 0.f, 0.f, 0.f};

    for (int ks = 0; ks < 10; ks++) {
        const int nb = ks & 1;
        const bool have = (ks + 1) < 10;
        float av[8];
        float4 bv0, bv1, bv2;
        if (have) {
            const int k0 = (ks + 1) << 5;
            const int gk = k0 + aq;
            if (gm < N && gk + 7 < DD) {
                float4 p0 = *(const float4*)(aggr + (size_t)gm * DD + gk);
                float4 p1 = *(const float4*)(aggr + (size_t)gm * DD + gk + 4);
                av[0]=p0.x; av[1]=p0.y; av[2]=p0.z; av[3]=p0.w;
                av[4]=p1.x; av[5]=p1.y; av[6]=p1.z; av[7]=p1.w;
            } else {
#pragma unroll
                for (int j = 0; j < 8; j++)
                    av[j] = (gm < N && gk + j < DD) ? aggr[(size_t)gm * DD + gk + j] : 0.f;
            }
            int c = t;
            bv0 = *(const float4*)(w1t + (size_t)(n0 + (c >> 2)) * 320 + k0 + ((c & 3) << 3));
            c = t + 256;
            bv1 = *(const float4*)(w1t + (size_t)(n0 + (c >> 2)) * 320 + k0 + ((c & 3) << 3));
            if (t < 128) {
                c = t + 512;
                bv2 = *(const float4*)(w1t + (size_t)(n0 + (c >> 2)) * 320 + k0 + ((c & 3) << 3));
            }
        }
        // compute current buffer
        bf16x8 a = *(const bf16x8*)&sA[nb][mrow][kb];
#pragma unroll
        for (int nt = 0; nt < 10; nt++) {
            bf16x8 b = *(const bf16x8*)&sB[nb][(nt << 4) + col][kb];
            acc[nt] = __builtin_amdgcn_mfma_f32_16x16x32_bf16(a, b, acc[nt], 0, 0, 0);
        }
        if (have) {
            bf16x8 v;
#pragma unroll
            for (int j = 0; j < 8; j++) v[j] = (short)f2bf(av[j]);
            *(bf16x8*)&sA[nb ^ 1][ar][aq] = v;
            int c = t;
            *(float4*)&sB[nb ^ 1][c >> 2][(c & 3) << 3] = bv0;
            c = t + 256;
            *(float4*)&sB[nb ^ 1][c >> 2][(c & 3) << 3] = bv1;
            if (t < 128) {
                c = t + 512;
                *(float4*)&sB[nb ^ 1][c >> 2][(c & 3) << 3] = bv2;
            }
        }
        __syncthreads();
    }

    // epilogue: bias + ReLU, store bf16
#pragma unroll
    for (int nt = 0; nt < 10; nt++) {
        int n = n0 + (nt << 4) + col;
        float bias = b1p[n];
        int mbase = m0 + (w << 4) + rq;
#pragma unroll
        for (int r = 0; r < 4; r++) {
            float vz = acc[nt][r] + bias;
            vz = fmaxf(vz, 0.f);
            hidden[(size_t)(mbase + r) * 640 + n] = f2bf(vz);
        }
    }
}

// ------------------------------------------- GEMM2 (MFMA bf16)
// h[m][n] = BN(hidden[m][:640] @ W2 + b2) (+ReLU)   n < 300, m < N
__global__ __launch_bounds__(256) void k_gemm2(const unsigned short* __restrict__ hidden, // [Npad][640]
                                               const short* __restrict__ w2t,             // [320][640]
                                               const float* __restrict__ b2,
                                               const float* __restrict__ bng, const float* __restrict__ bnb,
                                               const float* __restrict__ bnm, const float* __restrict__ bnv,
                                               float* __restrict__ h, int N, int relu_out) {
    __shared__ short sA[2][64][40];
    __shared__ short sB[2][160][40];
    const int t  = threadIdx.x;
    const int m0 = blockIdx.x * 64;
    const int n0 = blockIdx.y * 160;

    const int ar = t >> 2, aq = (t & 3) << 3;

    // ---- stage ks=0 ----
    {
        *(float4*)&sA[0][ar][aq] = *(const float4*)(hidden + (size_t)(m0 + ar) * 640 + aq);
#pragma unroll
        for (int i = 0; i < 3; i++) {
            int c = t + (i << 8);
            if (c < 640) {
                int br = c >> 2, bq = (c & 3) << 3;
                *(float4*)&sB[0][br][bq] = *(const float4*)(w2t + (size_t)(n0 + br) * 640 + bq);
            }
        }
    }
    __syncthreads();

    const int lane = t & 63;
    const int w    = t >> 6;
    const int mrow = (w << 4) + (lane & 15);
    const int kb   = (lane >> 4) << 3;
    const int col  = lane & 15;
    const int rq   = (lane >> 4) << 2;

    f32x4 acc[10];
#pragma unroll
    for (int nt = 0; nt < 10; nt++) acc[nt] = (f32x4){0.f, 0.f, 0.f, 0.f};

    for (int ks = 0; ks < 20; ks++) {
        const int nb = ks & 1;
        const bool have = (ks + 1) < 20;
        float4 avr, bv0, bv1, bv2;
        if (have) {
            const int k0 = (ks + 1) << 5;
            avr = *(const float4*)(hidden + (size_t)(m0 + ar) * 640 + k0 + aq);
            int c = t;
            bv0 = *(const float4*)(w2t + (size_t)(n0 + (c >> 2)) * 640 + k0 + ((c & 3) << 3));
            c = t + 256;
            bv1 = *(const float4*)(w2t + (size_t)(n0 + (c >> 2)) * 640 + k0 + ((c & 3) << 3));
            if (t < 128) {
                c = t + 512;
                bv2 = *(const float4*)(w2t + (size_t)(n0 + (c >> 2)) * 640 + k0 + ((c & 3) << 3));
            }
        }
        bf16x8 a = *(const bf16x8*)&sA[nb][mrow][kb];
#pragma unroll
        for (int nt = 0; nt < 10; nt++) {
            bf16x8 b = *(const bf16x8*)&sB[nb][(nt << 4) + col][kb];
            acc[nt] = __builtin_amdgcn_mfma_f32_16x16x32_bf16(a, b, acc[nt], 0, 0, 0);
        }
        if (have) {
            *(float4*)&sA[nb ^ 1][ar][aq] = avr;
            int c = t;
            *(float4*)&sB[nb ^ 1][c >> 2][(c & 3) << 3] = bv0;
            c = t + 256;
            *(float4*)&sB[nb ^ 1][c >> 2][(c & 3) << 3] = bv1;
            if (t < 128) {
                c = t + 512;
                *(float4*)&sB[nb ^ 1][c >> 2][(c & 3) << 3] = bv2;
            }
        }
        __syncthreads();
    }

    // epilogue: bias + BN (+ReLU), store f32 (masked)
#pragma unroll
    for (int nt = 0; nt < 10; nt++) {
        int n = n0 + (nt << 4) + col;
        bool nok = (n < DD);
        float bz = 0.f, sc = 1.f, mB = 0.f, bB = 0.f;
        if (nok) {
            bz = b2[n];
            sc = bng[n] * rsqrtf(bnv[n] + BN_EPS);
            mB = bnm[n];
            bB = bnb[n];
        }
        int mbase = m0 + (w << 4) + rq;
#pragma unroll
        for (int r = 0; r < 4; r++) {
            int m = mbase + r;
            if (nok && m < N) {
                float z = (acc[nt][r] + bz - mB) * sc + bB;
                if (relu_out) z = fmaxf(z, 0.f);
                h[(size_t)m * DD + n] = z;
            }
        }
    }
}

// ------------------------------------------- mean-pool scatter
__global__ __launch_bounds__(256) void k_pool(const float* __restrict__ z, const int* __restrict__ batch,
                                              float* __restrict__ pooled, int N) {
    int n = blockIdx.x;
    if (n >= N) return;
    int g = batch[n];
    const float* zr = z + (size_t)n * DD;
    float* pr = pooled + (size_t)g * DD;
    for (int d = threadIdx.x; d < DD; d += 256) atomicAdd(&pr[d], zr[d]);
}

// ------------------------------------------- virtual-node MLP (block/graph)
__global__ __launch_bounds__(256) void k_vn(const float* __restrict__ pooled, const float* __restrict__ counts,
                                            float* __restrict__ vnh,
                                            const float* __restrict__ w1, const float* __restrict__ b1,
                                            const float* __restrict__ lng, const float* __restrict__ lnb,
                                            const float* __restrict__ w2, const float* __restrict__ b2) {
    __shared__ float sV[DD];
    __shared__ float sT[DD];
    __shared__ float rs[4], rq[4];
    __shared__ float s_mu, s_rstd;
    int g = blockIdx.x, t = threadIdx.x;
    float inv = 1.0f / fmaxf(counts[g], 1.0f);
    for (int i = t; i < DD; i += 256)
        sV[i] = pooled[(size_t)g * DD + i] * inv + vnh[(size_t)g * DD + i];
    __syncthreads();

    const int j0 = t, j1 = t + 256;
    const bool g1 = (j1 < DD);
    float a0 = 0.f, a1 = 0.f;
    for (int k = 0; k < DD; k++) {
        float v = sV[k];
        const float* wr = w1 + (size_t)k * DD;
        a0 = fmaf(v, wr[j0], a0);
        a1 = fmaf(v, g1 ? wr[j1] : 0.f, a1);
    }
    float t0 = a0 + b1[j0];
    float t1 = g1 ? (a1 + b1[j1]) : 0.f;
    sT[j0] = t0;
    if (g1) sT[j1] = t1;
    __syncthreads();

    float ps = 0.f, pq = 0.f;
    for (int i = t; i < DD; i += 256) { float x = sT[i]; ps += x; pq += x * x; }
    for (int off = 32; off >= 1; off >>= 1) { ps += __shfl_down(ps, off, 64); pq += __shfl_down(pq, off, 64); }
    int wid = t >> 6, lane = t & 63;
    if (lane == 0) { rs[wid] = ps; rq[wid] = pq; }
    __syncthreads();
    if (t == 0) {
        float S = rs[0] + rs[1] + rs[2] + rs[3];
        float Q = rq[0] + rq[1] + rq[2] + rq[3];
        float mu = S / DD;
        float var = Q / DD - mu * mu;
        s_mu = mu;
        s_rstd = rsqrtf(var + BN_EPS);
    }
    __syncthreads();
    float mu = s_mu, rstd = s_rstd;
    float r0 = fmaxf((t0 - mu) * rstd * lng[j0] + lnb[j0], 0.f);
    float r1 = g1 ? fmaxf((t1 - mu) * rstd * lng[j1] + lnb[j1], 0.f) : 0.f;
    sT[j0] = r0;
    if (g1) sT[j1] = r1;
    __syncthreads();

    float o0 = 0.f, o1 = 0.f;
    for (int k = 0; k < DD; k++) {
        float v = sT[k];
        const float* wr = w2 + (size_t)k * DD;
        o0 = fmaf(v, wr[j0], o0);
        o1 = fmaf(v, g1 ? wr[j1] : 0.f, o1);
    }
    vnh[(size_t)g * DD + j0] = o0 + b2[j0];
    if (g1) vnh[(size_t)g * DD + j1] = o1 + b2[j1];
}

// ------------------------------------------- z += vn_h[batch]
__global__ __launch_bounds__(256) void k_vnadd(float* __restrict__ h, const int* __restrict__ batch,
                                               const float* __restrict__ vnh, int N) {
    int n = blockIdx.x;
    if (n >= N) return;
    int g = batch[n];
    float* hr = h + (size_t)n * DD;
    const float* vr = vnh + (size_t)g * DD;
    for (int d = threadIdx.x; d < DD; d += 256) hr[d] += vr[d];
}

extern "C" void kernel_launch(void* const* d_in, const int* in_sizes, int n_in,
                              void* d_out, int out_size, void* d_ws, size_t ws_size,
                              hipStream_t stream) {
    const int*   x_atom = (const int*)d_in[0];
    const int*   x_chir = (const int*)d_in[1];
    const int*   src    = (const int*)d_in[2];
    const int*   dst    = (const int*)d_in[3];
    const int*   ety    = (const int*)d_in[4];
    const int*   edir   = (const int*)d_in[5];
    const int*   batch  = (const int*)d_in[6];
    const float* emb1   = (const float*)d_in[7];
    const float* emb2   = (const float*)d_in[8];
    const float* e1     = (const float*)d_in[9];
    const float* e2     = (const float*)d_in[10];
    const float* w1     = (const float*)d_in[11];
    const float* b1     = (const float*)d_in[12];
    const float* w2     = (const float*)d_in[13];
    const float* b2     = (const float*)d_in[14];
    const float* bng    = (const float*)d_in[15];
    const float* bnb    = (const float*)d_in[16];
    const float* bnm    = (const float*)d_in[17];
    const float* bnv    = (const float*)d_in[18];
    const float* vne    = (const float*)d_in[19];
    const float* vw1    = (const float*)d_in[20];
    const float* vb1    = (const float*)d_in[21];
    const float* lng    = (const float*)d_in[22];
    const float* lnb    = (const float*)d_in[23];
    const float* vw2    = (const float*)d_in[24];
    const float* vb2    = (const float*)d_in[25];

    const int N = in_sizes[0];
    const int E = in_sizes[2];
    const int gx = (N + 63) / 64;
    const int Npad = gx * 64;

    float* h = (float*)d_out;                                   // [N, D]

    // workspace layout (all 16B-aligned)
    float*          aggr   = (float*)d_ws;                      // [N, 300] f32
    unsigned short* hidden = (unsigned short*)(aggr + (size_t)N * DD);  // [Npad, 640] bf16
    short*          w1t    = (short*)(hidden + (size_t)Npad * 640);     // [L,640,320] bf16
    short*          w2t    = w1t + (size_t)LL * 640 * 320;              // [L,320,640] bf16
    float*          b1p    = (float*)(w2t + (size_t)LL * 320 * 640);    // [L,640]
    float*          pooled = b1p + (size_t)LL * 640;            // [G, 300]
    float*          vnh    = pooled + (size_t)GG * DD;          // [G, 300]
    float*          counts = vnh + (size_t)GG * DD;             // [G]

    // weight conversion (bf16, transposed, zero-padded) — every call, cheap
    k_convw<<<dim3(640, LL), 256, 0, stream>>>(w1, w1t, DD, DD2, 320, 640);
    k_convw<<<dim3(320, LL), 256, 0, stream>>>(w2, w2t, DD2, DD, 640, 320);
    k_padb<<<dim3(3, LL), 256, 0, stream>>>(b1, b1p);

    hipMemsetAsync(counts, 0, GG * sizeof(float), stream);
    k_counts<<<(N + 255) / 256, 256, 0, stream>>>(batch, counts, N);
    k_init_h<<<N, 256, 0, stream>>>(x_atom, x_chir, emb1, emb2, vne, h, N);
    k_init_vn<<<GG, 256, 0, stream>>>(vne, vnh);

    for (int l = 0; l < LL; l++) {
        k_self<<<N, 256, 0, stream>>>(h, aggr,
                                      e1 + ((size_t)l * 6 + 4) * DD,
                                      e2 + ((size_t)l * 3 + 0) * DD, N);
        k_scatter<<<E, 256, 0, stream>>>(h, aggr, src, dst, ety, edir,
                                         e1 + (size_t)l * 6 * DD,
                                         e2 + (size_t)l * 3 * DD, E);
        k_gemm1<<<dim3(gx, 4), 256, 0, stream>>>(aggr, w1t + (size_t)l * 640 * 320,
                                                 b1p + (size_t)l * 640, hidden, N);
        k_gemm2<<<dim3(gx, 2), 256, 0, stream>>>(hidden, w2t + (size_t)l * 320 * 640,
                                                 b2 + (size_t)l * DD,
                                                 bng + (size_t)l * DD, bnb + (size_t)l * DD,
                                                 bnm + (size_t)l * DD, bnv + (size_t)l * DD,
                                                 h, N, (l < LL - 1) ? 1 : 0);
        if (l < LL - 1) {
            hipMemsetAsync(pooled, 0, (size_t)GG * DD * sizeof(float), stream);
            k_pool<<<N, 256, 0, stream>>>(h, batch, pooled, N);
            k_vn<<<GG, 256, 0, stream>>>(pooled, counts, vnh,
                                         vw1 + (size_t)l * DD * DD, vb1 + (size_t)l * DD,
                                         lng + (size_t)l * DD, lnb + (size_t)l * DD,
                                         vw2 + (size_t)l * DD * DD, vb2 + (size_t)l * DD);
            k_vnadd<<<N, 256, 0, stream>>>(h, batch, vnh, N);
        }
    }
}

// Round 3
// 3129.460 us; speedup vs baseline: 3.5021x; 1.4585x over previous
//
#include <hip/hip_runtime.h>

// Problem constants (fixed by the reference)
#define DD   300     // emb dim
#define DD2  600     // 2*D
#define GG   4000    // graphs
#define LL   5       // layers
#define BN_EPS 1e-5f

typedef float f32x4  __attribute__((ext_vector_type(4)));
typedef short bf16x8 __attribute__((ext_vector_type(8)));

__device__ __forceinline__ unsigned short f2bf(float f) {
    unsigned int x = __float_as_uint(f);
    unsigned int r = (x + 0x7FFFu + ((x >> 16) & 1u)) >> 16;   // RTNE
    return (unsigned short)r;
}

// ---------------------------------------------------------------- counts
__global__ __launch_bounds__(256) void k_counts(const int* __restrict__ batch,
                                                float* __restrict__ counts, int N) {
    int i = blockIdx.x * 256 + threadIdx.x;
    if (i < N) atomicAdd(&counts[batch[i]], 1.0f);
}

// ---------------------------------------------------------------- CSR build
__global__ __launch_bounds__(256) void k_hist(const int* __restrict__ dst, int* __restrict__ deg, int E) {
    int e = blockIdx.x * 256 + threadIdx.x;
    if (e < E) atomicAdd(&deg[dst[e]], 1);
}

// exclusive scan deg[N] -> rowptr[N+1]; single block of 1024 threads
__global__ __launch_bounds__(1024) void k_scan(const int* __restrict__ deg, int* __restrict__ rowptr, int N) {
    __shared__ int sums[1024];
    const int t = threadIdx.x;
    const int chunk = (N + 1023) / 1024;
    const int s0 = t * chunk;
    const int s1 = min(s0 + chunk, N);
    int local = 0;
    for (int i = s0; i < s1; i++) local += deg[i];
    sums[t] = local;
    __syncthreads();
    for (int off = 1; off < 1024; off <<= 1) {
        int v = (t >= off) ? sums[t - off] : 0;
        __syncthreads();
        sums[t] += v;
        __syncthreads();
    }
    int run = (t == 0) ? 0 : sums[t - 1];
    for (int i = s0; i < s1; i++) { rowptr[i] = run; run += deg[i]; }
    if (t == 1023) rowptr[N] = run;   // == E
}

// place edges grouped by dst; einfo = src | (code<<20), code = type*3+dir
__global__ __launch_bounds__(256) void k_place(const int* __restrict__ src, const int* __restrict__ dst,
                                               const int* __restrict__ ety, const int* __restrict__ edir,
                                               const int* __restrict__ rowptr, int* __restrict__ cursor,
                                               int* __restrict__ einfo, int E) {
    int e = blockIdx.x * 256 + threadIdx.x;
    if (e >= E) return;
    int d = dst[e];
    int pos = rowptr[d] + atomicAdd(&cursor[d], 1);
    einfo[pos] = src[e] | ((ety[e] * 3 + edir[e]) << 20);
}

// ---------------------------------------------------------------- comb tables
// comb[l][c][d] = e1[l][c/3][d] + e2[l][c%3][d], c in [0,18)
__global__ __launch_bounds__(256) void k_comb(const float* __restrict__ e1, const float* __restrict__ e2,
                                              float* __restrict__ comb) {
    int c = blockIdx.x, l = blockIdx.y;
    const float* r1 = e1 + ((size_t)l * 6 + (c / 3)) * DD;
    const float* r2 = e2 + ((size_t)l * 3 + (c % 3)) * DD;
    float* out = comb + ((size_t)l * 18 + c) * DD;
    for (int d = threadIdx.x; d < DD; d += 256) out[d] = r1[d] + r2[d];
}

// ---------------------------------------------------------------- h init
__global__ __launch_bounds__(256) void k_init_h(const int* __restrict__ xa, const int* __restrict__ xc,
                                                const float* __restrict__ emb1, const float* __restrict__ emb2,
                                                const float* __restrict__ vne,
                                                float* __restrict__ h, int N) {
    int n = blockIdx.x;
    if (n >= N) return;
    int a = xa[n], c = xc[n];
    for (int d = threadIdx.x; d < DD; d += 256)
        h[(size_t)n * DD + d] = emb1[(size_t)a * DD + d] + emb2[(size_t)c * DD + d] + vne[d];
}

__global__ __launch_bounds__(256) void k_init_vn(const float* __restrict__ vne, float* __restrict__ vnh) {
    int g = blockIdx.x;
    for (int d = threadIdx.x; d < DD; d += 256) vnh[(size_t)g * DD + d] = vne[d];
}

// ---------------------------------------------------------------- fused aggregation (CSR gather)
// aggrb[n][0:320) = bf16( h[n] + comb[12] + sum_in(h[src] + comb[code]) ), zero-padded
// one wave per node
__global__ __launch_bounds__(256) void k_aggr(const float* __restrict__ h,
                                              const int* __restrict__ rowptr, const int* __restrict__ einfo,
                                              const float* __restrict__ comb,
                                              unsigned short* __restrict__ aggrb, int N, int Npad) {
    const int node = blockIdx.x * 4 + (threadIdx.x >> 6);
    const int lane = threadIdx.x & 63;
    if (node >= Npad) return;
    unsigned short* out = aggrb + (size_t)node * 320;
    if (node >= N) {
#pragma unroll
        for (int j = 0; j < 5; j++) out[lane + 64 * j] = 0;
        return;
    }
    float acc[5];
    {
        const float* hs = h + (size_t)node * DD;
        const float* sc = comb + 12 * DD;   // self-loop: type 4, dir 0
#pragma unroll
        for (int j = 0; j < 5; j++) {
            int d = lane + 64 * j;
            acc[j] = (d < DD) ? hs[d] + sc[d] : 0.f;
        }
    }
    const int p0 = rowptr[node], p1 = rowptr[node + 1];
    for (int p = p0; p < p1; p++) {
        int info = einfo[p];
        const float* hr = h + (size_t)(info & 0xFFFFF) * DD;
        const float* cr = comb + (size_t)(info >> 20) * DD;
#pragma unroll
        for (int j = 0; j < 5; j++) {
            int d = lane + 64 * j;
            if (d < DD) acc[j] += hr[d] + cr[d];
        }
    }
#pragma unroll
    for (int j = 0; j < 5; j++) {
        int d = lane + 64 * j;
        out[d] = (d < DD) ? f2bf(acc[j]) : (unsigned short)0;
    }
}

// ------------------------------------------- weight transpose+pad -> bf16
__global__ __launch_bounds__(256) void k_convw(const float* __restrict__ w, short* __restrict__ wt,
                                               int K, int Nn, int KP, int NP) {
    int n = blockIdx.x;
    int l = blockIdx.y;
    const float* wl = w + (size_t)l * K * Nn;
    short* wtl = wt + (size_t)l * NP * KP;
    for (int k = threadIdx.x; k < KP; k += 256) {
        float v = (k < K && n < Nn) ? wl[(size_t)k * Nn + n] : 0.f;
        wtl[(size_t)n * KP + k] = (short)f2bf(v);
    }
}

__global__ __launch_bounds__(256) void k_padb(const float* __restrict__ b, float* __restrict__ bp) {
    int l = blockIdx.y;
    int n = blockIdx.x * 256 + threadIdx.x;
    if (n < 640) bp[(size_t)l * 640 + n] = (n < DD2) ? b[(size_t)l * DD2 + n] : 0.f;
}

// ------------------------------------------- GEMM1 (MFMA bf16)
// hidden = relu(aggrb[Npad][320] @ W1t^T + b1), store bf16 [Npad][640]
__global__ __launch_bounds__(256) void k_gemm1(const unsigned short* __restrict__ aggrb,
                                               const short* __restrict__ w1t,   // [640][320]
                                               const float* __restrict__ b1p,   // [640]
                                               unsigned short* __restrict__ hidden) {
    __shared__ short sA[2][64][40];
    __shared__ short sB[2][160][40];
    const int t  = threadIdx.x;
    const int m0 = blockIdx.x * 64;
    const int n0 = blockIdx.y * 160;
    const int ar = t >> 2, aq = (t & 3) << 3;

    {
        *(float4*)&sA[0][ar][aq] = *(const float4*)(aggrb + (size_t)(m0 + ar) * 320 + aq);
#pragma unroll
        for (int i = 0; i < 3; i++) {
            int c = t + (i << 8);
            if (c < 640) {
                int br = c >> 2, bq = (c & 3) << 3;
                *(float4*)&sB[0][br][bq] = *(const float4*)(w1t + (size_t)(n0 + br) * 320 + bq);
            }
        }
    }
    __syncthreads();

    const int lane = t & 63;
    const int w    = t >> 6;
    const int mrow = (w << 4) + (lane & 15);
    const int kb   = (lane >> 4) << 3;
    const int col  = lane & 15;
    const int rq   = (lane >> 4) << 2;

    f32x4 acc[10];
#pragma unroll
    for (int nt = 0; nt < 10; nt++) acc[nt] = (f32x4){0.f, 0.f, 0.f, 0.f};

    for (int ks = 0; ks < 10; ks++) {
        const int nb = ks & 1;
        const bool have = (ks + 1) < 10;
        float4 avr, bv0, bv1, bv2;
        if (have) {
            const int k0 = (ks + 1) << 5;
            avr = *(const float4*)(aggrb + (size_t)(m0 + ar) * 320 + k0 + aq);
            int c = t;
            bv0 = *(const float4*)(w1t + (size_t)(n0 + (c >> 2)) * 320 + k0 + ((c & 3) << 3));
            c = t + 256;
            bv1 = *(const float4*)(w1t + (size_t)(n0 + (c >> 2)) * 320 + k0 + ((c & 3) << 3));
            if (t < 128) {
                c = t + 512;
                bv2 = *(const float4*)(w1t + (size_t)(n0 + (c >> 2)) * 320 + k0 + ((c & 3) << 3));
            }
        }
        bf16x8 a = *(const bf16x8*)&sA[nb][mrow][kb];
#pragma unroll
        for (int nt = 0; nt < 10; nt++) {
            bf16x8 b = *(const bf16x8*)&sB[nb][(nt << 4) + col][kb];
            acc[nt] = __builtin_amdgcn_mfma_f32_16x16x32_bf16(a, b, acc[nt], 0, 0, 0);
        }
        if (have) {
            *(float4*)&sA[nb ^ 1][ar][aq] = avr;
            int c = t;
            *(float4*)&sB[nb ^ 1][c >> 2][(c & 3) << 3] = bv0;
            c = t + 256;
            *(float4*)&sB[nb ^ 1][c >> 2][(c & 3) << 3] = bv1;
            if (t < 128) {
                c = t + 512;
                *(float4*)&sB[nb ^ 1][c >> 2][(c & 3) << 3] = bv2;
            }
        }
        __syncthreads();
    }

#pragma unroll
    for (int nt = 0; nt < 10; nt++) {
        int n = n0 + (nt << 4) + col;
        float bias = b1p[n];
        int mbase = m0 + (w << 4) + rq;
#pragma unroll
        for (int r = 0; r < 4; r++) {
            float vz = fmaxf(acc[nt][r] + bias, 0.f);
            hidden[(size_t)(mbase + r) * 640 + n] = f2bf(vz);
        }
    }
}

// ------------------------------------------- GEMM2 (MFMA bf16)
__global__ __launch_bounds__(256) void k_gemm2(const unsigned short* __restrict__ hidden, // [Npad][640]
                                               const short* __restrict__ w2t,             // [320][640]
                                               const float* __restrict__ b2,
                                               const float* __restrict__ bng, const float* __restrict__ bnb,
                                               const float* __restrict__ bnm, const float* __restrict__ bnv,
                                               float* __restrict__ h, int N, int relu_out) {
    __shared__ short sA[2][64][40];
    __shared__ short sB[2][160][40];
    const int t  = threadIdx.x;
    const int m0 = blockIdx.x * 64;
    const int n0 = blockIdx.y * 160;
    const int ar = t >> 2, aq = (t & 3) << 3;

    {
        *(float4*)&sA[0][ar][aq] = *(const float4*)(hidden + (size_t)(m0 + ar) * 640 + aq);
#pragma unroll
        for (int i = 0; i < 3; i++) {
            int c = t + (i << 8);
            if (c < 640) {
                int br = c >> 2, bq = (c & 3) << 3;
                *(float4*)&sB[0][br][bq] = *(const float4*)(w2t + (size_t)(n0 + br) * 640 + bq);
            }
        }
    }
    __syncthreads();

    const int lane = t & 63;
    const int w    = t >> 6;
    const int mrow = (w << 4) + (lane & 15);
    const int kb   = (lane >> 4) << 3;
    const int col  = lane & 15;
    const int rq   = (lane >> 4) << 2;

    f32x4 acc[10];
#pragma unroll
    for (int nt = 0; nt < 10; nt++) acc[nt] = (f32x4){0.f, 0.f, 0.f, 0.f};

    for (int ks = 0; ks < 20; ks++) {
        const int nb = ks & 1;
        const bool have = (ks + 1) < 20;
        float4 avr, bv0, bv1, bv2;
        if (have) {
            const int k0 = (ks + 1) << 5;
            avr = *(const float4*)(hidden + (size_t)(m0 + ar) * 640 + k0 + aq);
            int c = t;
            bv0 = *(const float4*)(w2t + (size_t)(n0 + (c >> 2)) * 640 + k0 + ((c & 3) << 3));
            c = t + 256;
            bv1 = *(const float4*)(w2t + (size_t)(n0 + (c >> 2)) * 640 + k0 + ((c & 3) << 3));
            if (t < 128) {
                c = t + 512;
                bv2 = *(const float4*)(w2t + (size_t)(n0 + (c >> 2)) * 640 + k0 + ((c & 3) << 3));
            }
        }
        bf16x8 a = *(const bf16x8*)&sA[nb][mrow][kb];
#pragma unroll
        for (int nt = 0; nt < 10; nt++) {
            bf16x8 b = *(const bf16x8*)&sB[nb][(nt << 4) + col][kb];
            acc[nt] = __builtin_amdgcn_mfma_f32_16x16x32_bf16(a, b, acc[nt], 0, 0, 0);
        }
        if (have) {
            *(float4*)&sA[nb ^ 1][ar][aq] = avr;
            int c = t;
            *(float4*)&sB[nb ^ 1][c >> 2][(c & 3) << 3] = bv0;
            c = t + 256;
            *(float4*)&sB[nb ^ 1][c >> 2][(c & 3) << 3] = bv1;
            if (t < 128) {
                c = t + 512;
                *(float4*)&sB[nb ^ 1][c >> 2][(c & 3) << 3] = bv2;
            }
        }
        __syncthreads();
    }

#pragma unroll
    for (int nt = 0; nt < 10; nt++) {
        int n = n0 + (nt << 4) + col;
        bool nok = (n < DD);
        float bz = 0.f, sc = 1.f, mB = 0.f, bB = 0.f;
        if (nok) {
            bz = b2[n];
            sc = bng[n] * rsqrtf(bnv[n] + BN_EPS);
            mB = bnm[n];
            bB = bnb[n];
        }
        int mbase = m0 + (w << 4) + rq;
#pragma unroll
        for (int r = 0; r < 4; r++) {
            int m = mbase + r;
            if (nok && m < N) {
                float z = (acc[nt][r] + bz - mB) * sc + bB;
                if (relu_out) z = fmaxf(z, 0.f);
                h[(size_t)m * DD + n] = z;
            }
        }
    }
}

// ------------------------------------------- mean-pool scatter
__global__ __launch_bounds__(256) void k_pool(const float* __restrict__ z, const int* __restrict__ batch,
                                              float* __restrict__ pooled, int N) {
    int n = blockIdx.x;
    if (n >= N) return;
    int g = batch[n];
    const float* zr = z + (size_t)n * DD;
    float* pr = pooled + (size_t)g * DD;
    for (int d = threadIdx.x; d < DD; d += 256) atomicAdd(&pr[d], zr[d]);
}

// ------------------------------------------- virtual-node MLP (block/graph)
__global__ __launch_bounds__(256) void k_vn(const float* __restrict__ pooled, const float* __restrict__ counts,
                                            float* __restrict__ vnh,
                                            const float* __restrict__ w1, const float* __restrict__ b1,
                                            const float* __restrict__ lng, const float* __restrict__ lnb,
                                            const float* __restrict__ w2, const float* __restrict__ b2) {
    __shared__ float sV[DD];
    __shared__ float sT[DD];
    __shared__ float rs[4], rq[4];
    __shared__ float s_mu, s_rstd;
    int g = blockIdx.x, t = threadIdx.x;
    float inv = 1.0f / fmaxf(counts[g], 1.0f);
    for (int i = t; i < DD; i += 256)
        sV[i] = pooled[(size_t)g * DD + i] * inv + vnh[(size_t)g * DD + i];
    __syncthreads();

    const int j0 = t, j1 = t + 256;
    const bool g1 = (j1 < DD);
    float a0 = 0.f, a1 = 0.f;
    for (int k = 0; k < DD; k++) {
        float v = sV[k];
        const float* wr = w1 + (size_t)k * DD;
        a0 = fmaf(v, wr[j0], a0);
        a1 = fmaf(v, g1 ? wr[j1] : 0.f, a1);
    }
    float t0 = a0 + b1[j0];
    float t1 = g1 ? (a1 + b1[j1]) : 0.f;
    sT[j0] = t0;
    if (g1) sT[j1] = t1;
    __syncthreads();

    float ps = 0.f, pq = 0.f;
    for (int i = t; i < DD; i += 256) { float x = sT[i]; ps += x; pq += x * x; }
    for (int off = 32; off >= 1; off >>= 1) { ps += __shfl_down(ps, off, 64); pq += __shfl_down(pq, off, 64); }
    int wid = t >> 6, lane = t & 63;
    if (lane == 0) { rs[wid] = ps; rq[wid] = pq; }
    __syncthreads();
    if (t == 0) {
        float S = rs[0] + rs[1] + rs[2] + rs[3];
        float Q = rq[0] + rq[1] + rq[2] + rq[3];
        float mu = S / DD;
        float var = Q / DD - mu * mu;
        s_mu = mu;
        s_rstd = rsqrtf(var + BN_EPS);
    }
    __syncthreads();
    float mu = s_mu, rstd = s_rstd;
    float r0 = fmaxf((t0 - mu) * rstd * lng[j0] + lnb[j0], 0.f);
    float r1 = g1 ? fmaxf((t1 - mu) * rstd * lng[j1] + lnb[j1], 0.f) : 0.f;
    sT[j0] = r0;
    if (g1) sT[j1] = r1;
    __syncthreads();

    float o0 = 0.f, o1 = 0.f;
    for (int k = 0; k < DD; k++) {
        float v = sT[k];
        const float* wr = w2 + (size_t)k * DD;
        o0 = fmaf(v, wr[j0], o0);
        o1 = fmaf(v, g1 ? wr[j1] : 0.f, o1);
    }
    vnh[(size_t)g * DD + j0] = o0 + b2[j0];
    if (g1) vnh[(size_t)g * DD + j1] = o1 + b2[j1];
}

// ------------------------------------------- z += vn_h[batch]
__global__ __launch_bounds__(256) void k_vnadd(float* __restrict__ h, const int* __restrict__ batch,
                                               const float* __restrict__ vnh, int N) {
    int n = blockIdx.x;
    if (n >= N) return;
    int g = batch[n];
    float* hr = h + (size_t)n * DD;
    const float* vr = vnh + (size_t)g * DD;
    for (int d = threadIdx.x; d < DD; d += 256) hr[d] += vr[d];
}

extern "C" void kernel_launch(void* const* d_in, const int* in_sizes, int n_in,
                              void* d_out, int out_size, void* d_ws, size_t ws_size,
                              hipStream_t stream) {
    const int*   x_atom = (const int*)d_in[0];
    const int*   x_chir = (const int*)d_in[1];
    const int*   src    = (const int*)d_in[2];
    const int*   dst    = (const int*)d_in[3];
    const int*   ety    = (const int*)d_in[4];
    const int*   edir   = (const int*)d_in[5];
    const int*   batch  = (const int*)d_in[6];
    const float* emb1   = (const float*)d_in[7];
    const float* emb2   = (const float*)d_in[8];
    const float* e1     = (const float*)d_in[9];
    const float* e2     = (const float*)d_in[10];
    const float* w1     = (const float*)d_in[11];
    const float* b1     = (const float*)d_in[12];
    const float* w2     = (const float*)d_in[13];
    const float* b2     = (const float*)d_in[14];
    const float* bng    = (const float*)d_in[15];
    const float* bnb    = (const float*)d_in[16];
    const float* bnm    = (const float*)d_in[17];
    const float* bnv    = (const float*)d_in[18];
    const float* vne    = (const float*)d_in[19];
    const float* vw1    = (const float*)d_in[20];
    const float* vb1    = (const float*)d_in[21];
    const float* lng    = (const float*)d_in[22];
    const float* lnb    = (const float*)d_in[23];
    const float* vw2    = (const float*)d_in[24];
    const float* vb2    = (const float*)d_in[25];

    const int N = in_sizes[0];
    const int E = in_sizes[2];
    const int gx = (N + 63) / 64;
    const int Npad = gx * 64;

    float* h = (float*)d_out;                                   // [N, D]

    // workspace layout (16B-aligned segments first, int arrays last)
    unsigned short* aggrb  = (unsigned short*)d_ws;                      // [Npad,320] bf16
    unsigned short* hidden = aggrb + (size_t)Npad * 320;                 // [Npad,640] bf16
    short*          w1t    = (short*)(hidden + (size_t)Npad * 640);      // [L,640,320] bf16
    short*          w2t    = w1t + (size_t)LL * 640 * 320;               // [L,320,640] bf16
    float*          b1p    = (float*)(w2t + (size_t)LL * 320 * 640);     // [L,640]
    float*          comb   = b1p + (size_t)LL * 640;                     // [L,18,300]
    float*          pooled = comb + (size_t)LL * 18 * DD;                // [G,300]
    float*          vnh    = pooled + (size_t)GG * DD;                   // [G,300]
    float*          counts = vnh + (size_t)GG * DD;                      // [G]
    int*            deg    = (int*)(counts + GG);                        // [N]
    int*            rowptr = deg + N;                                    // [N+1]
    int*            cursor = rowptr + (N + 1);                           // [N]
    int*            einfo  = cursor + N;                                 // [E]

    // --- weight prep ---
    k_convw<<<dim3(640, LL), 256, 0, stream>>>(w1, w1t, DD, DD2, 320, 640);
    k_convw<<<dim3(320, LL), 256, 0, stream>>>(w2, w2t, DD2, DD, 640, 320);
    k_padb<<<dim3(3, LL), 256, 0, stream>>>(b1, b1p);
    k_comb<<<dim3(18, LL), 256, 0, stream>>>(e1, e2, comb);

    // --- CSR build ---
    hipMemsetAsync(deg, 0, (size_t)N * sizeof(int), stream);
    hipMemsetAsync(cursor, 0, (size_t)N * sizeof(int), stream);
    hipMemsetAsync(counts, 0, GG * sizeof(float), stream);
    k_hist<<<(E + 255) / 256, 256, 0, stream>>>(dst, deg, E);
    k_counts<<<(N + 255) / 256, 256, 0, stream>>>(batch, counts, N);
    k_scan<<<1, 1024, 0, stream>>>(deg, rowptr, N);
    k_place<<<(E + 255) / 256, 256, 0, stream>>>(src, dst, ety, edir, rowptr, cursor, einfo, E);

    k_init_h<<<N, 256, 0, stream>>>(x_atom, x_chir, emb1, emb2, vne, h, N);
    k_init_vn<<<GG, 256, 0, stream>>>(vne, vnh);

    for (int l = 0; l < LL; l++) {
        k_aggr<<<Npad / 4, 256, 0, stream>>>(h, rowptr, einfo, comb + (size_t)l * 18 * DD,
                                             aggrb, N, Npad);
        k_gemm1<<<dim3(gx, 4), 256, 0, stream>>>(aggrb, w1t + (size_t)l * 640 * 320,
                                                 b1p + (size_t)l * 640, hidden);
        k_gemm2<<<dim3(gx, 2), 256, 0, stream>>>(hidden, w2t + (size_t)l * 320 * 640,
                                                 b2 + (size_t)l * DD,
                                                 bng + (size_t)l * DD, bnb + (size_t)l * DD,
                                                 bnm + (size_t)l * DD, bnv + (size_t)l * DD,
                                                 h, N, (l < LL - 1) ? 1 : 0);
        if (l < LL - 1) {
            hipMemsetAsync(pooled, 0, (size_t)GG * DD * sizeof(float), stream);
            k_pool<<<N, 256, 0, stream>>>(h, batch, pooled, N);
            k_vn<<<GG, 256, 0, stream>>>(pooled, counts, vnh,
                                         vw1 + (size_t)l * DD * DD, vb1 + (size_t)l * DD,
                                         lng + (size_t)l * DD, lnb + (size_t)l * DD,
                                         vw2 + (size_t)l * DD * DD, vb2 + (size_t)l * DD);
            k_vnadd<<<N, 256, 0, stream>>>(h, batch, vnh, N);
        }
    }
}

// Round 4
// 2496.631 us; speedup vs baseline: 4.3898x; 1.2535x over previous
//
#include <hip/hip_runtime.h>

// Problem constants (fixed by the reference)
#define DD   300     // emb dim
#define DD2  600     // 2*D
#define GG   4000    // graphs
#define LL   5       // layers
#define BN_EPS 1e-5f

typedef float f32x4  __attribute__((ext_vector_type(4)));
typedef short bf16x8 __attribute__((ext_vector_type(8)));

__device__ __forceinline__ unsigned short f2bf(float f) {
    unsigned int x = __float_as_uint(f);
    unsigned int r = (x + 0x7FFFu + ((x >> 16) & 1u)) >> 16;   // RTNE
    return (unsigned short)r;
}

// ---------------------------------------------------------------- histogram
__global__ __launch_bounds__(256) void k_hist(const int* __restrict__ idx, int* __restrict__ cnt, int n) {
    int i = blockIdx.x * 256 + threadIdx.x;
    if (i < n) atomicAdd(&cnt[idx[i]], 1);
}

// ---------------------------------------------------------------- hierarchical exclusive scan
// pass 1: per-block (256 elems) sums
__global__ __launch_bounds__(256) void k_scan1(const int* __restrict__ in, int* __restrict__ bsum, int n) {
    int t = threadIdx.x;
    int i = blockIdx.x * 256 + t;
    int v = (i < n) ? in[i] : 0;
    for (int off = 32; off >= 1; off >>= 1) v += __shfl_down(v, off, 64);
    __shared__ int s[4];
    if ((t & 63) == 0) s[t >> 6] = v;
    __syncthreads();
    if (t == 0) bsum[blockIdx.x] = s[0] + s[1] + s[2] + s[3];
}
// pass 2: exclusive scan of block sums in-place (nb <= 1024)
__global__ __launch_bounds__(1024) void k_scan2(int* __restrict__ bsum, int nb) {
    __shared__ int s[1024];
    int t = threadIdx.x;
    int v = (t < nb) ? bsum[t] : 0;
    s[t] = v;
    __syncthreads();
    for (int off = 1; off < 1024; off <<= 1) {
        int u = (t >= off) ? s[t - off] : 0;
        __syncthreads();
        s[t] += u;
        __syncthreads();
    }
    if (t < nb) bsum[t] = s[t] - v;   // exclusive
}
// pass 3: in-block exclusive scan + block offset; out[n] = total
__global__ __launch_bounds__(256) void k_scan3(const int* __restrict__ in, const int* __restrict__ boff,
                                               int* __restrict__ out, int n, int total) {
    __shared__ int s[256];
    int t = threadIdx.x;
    int i = blockIdx.x * 256 + t;
    int v = (i < n) ? in[i] : 0;
    s[t] = v;
    __syncthreads();
    for (int off = 1; off < 256; off <<= 1) {
        int u = (t >= off) ? s[t - off] : 0;
        __syncthreads();
        s[t] += u;
        __syncthreads();
    }
    if (i < n) out[i] = boff[blockIdx.x] + s[t] - v;
    if (i == 0) out[n] = total;
}

// place edges grouped by dst; einfo = src | (code<<20), code = type*3+dir
__global__ __launch_bounds__(256) void k_place(const int* __restrict__ src, const int* __restrict__ dst,
                                               const int* __restrict__ ety, const int* __restrict__ edir,
                                               const int* __restrict__ rowptr, int* __restrict__ cursor,
                                               int* __restrict__ einfo, int E) {
    int e = blockIdx.x * 256 + threadIdx.x;
    if (e >= E) return;
    int d = dst[e];
    int pos = rowptr[d] + atomicAdd(&cursor[d], 1);
    einfo[pos] = src[e] | ((ety[e] * 3 + edir[e]) << 20);
}

// ---------------------------------------------------------------- comb tables
__global__ __launch_bounds__(256) void k_comb(const float* __restrict__ e1, const float* __restrict__ e2,
                                              float* __restrict__ comb) {
    int c = blockIdx.x, l = blockIdx.y;
    const float* r1 = e1 + ((size_t)l * 6 + (c / 3)) * DD;
    const float* r2 = e2 + ((size_t)l * 3 + (c % 3)) * DD;
    float* out = comb + ((size_t)l * 18 + c) * DD;
    for (int d = threadIdx.x; d < DD; d += 256) out[d] = r1[d] + r2[d];
}

// ---------------------------------------------------------------- h init
__global__ __launch_bounds__(256) void k_init_h(const int* __restrict__ xa, const int* __restrict__ xc,
                                                const float* __restrict__ emb1, const float* __restrict__ emb2,
                                                const float* __restrict__ vne,
                                                float* __restrict__ h, int N) {
    int n = blockIdx.x;
    if (n >= N) return;
    int a = xa[n], c = xc[n];
    for (int d = threadIdx.x; d < DD; d += 256)
        h[(size_t)n * DD + d] = emb1[(size_t)a * DD + d] + emb2[(size_t)c * DD + d] + vne[d];
}

__global__ __launch_bounds__(256) void k_init_vn(const float* __restrict__ vne, float* __restrict__ vnh) {
    int g = blockIdx.x;
    for (int d = threadIdx.x; d < DD; d += 256) vnh[(size_t)g * DD + d] = vne[d];
}

// ---------------------------------------------------------------- fused aggregation (CSR gather)
// aggrb[n] = bf16( heff[n] + comb[12] + sum_in(heff[src] + comb[code]) ), heff = h + vnh[batch]
// one wave per node
__global__ __launch_bounds__(256) void k_aggr(const float* __restrict__ h,
                                              const int* __restrict__ rowptr, const int* __restrict__ einfo,
                                              const float* __restrict__ comb,
                                              const int* __restrict__ batch, const float* __restrict__ vnh,
                                              int use_vn,
                                              unsigned short* __restrict__ aggrb, int N, int Npad) {
    const int node = blockIdx.x * 4 + (threadIdx.x >> 6);
    const int lane = threadIdx.x & 63;
    if (node >= Npad) return;
    unsigned short* out = aggrb + (size_t)node * 320;
    if (node >= N) {
#pragma unroll
        for (int j = 0; j < 5; j++) out[lane + 64 * j] = 0;
        return;
    }
    float acc[5];
    const float* sc = comb + 12 * DD;   // self-loop: type 4, dir 0
    const int p0 = rowptr[node], p1 = rowptr[node + 1];
    if (use_vn) {
        {
            const float* hs = h + (size_t)node * DD;
            const float* vs = vnh + (size_t)batch[node] * DD;
#pragma unroll
            for (int j = 0; j < 5; j++) {
                int d = lane + 64 * j;
                acc[j] = (d < DD) ? hs[d] + sc[d] + vs[d] : 0.f;
            }
        }
        for (int p = p0; p < p1; p++) {
            int info = einfo[p];
            int s = info & 0xFFFFF;
            const float* hr = h + (size_t)s * DD;
            const float* cr = comb + (size_t)(info >> 20) * DD;
            const float* vr = vnh + (size_t)batch[s] * DD;
#pragma unroll
            for (int j = 0; j < 5; j++) {
                int d = lane + 64 * j;
                if (d < DD) acc[j] += hr[d] + cr[d] + vr[d];
            }
        }
    } else {
        {
            const float* hs = h + (size_t)node * DD;
#pragma unroll
            for (int j = 0; j < 5; j++) {
                int d = lane + 64 * j;
                acc[j] = (d < DD) ? hs[d] + sc[d] : 0.f;
            }
        }
        for (int p = p0; p < p1; p++) {
            int info = einfo[p];
            const float* hr = h + (size_t)(info & 0xFFFFF) * DD;
            const float* cr = comb + (size_t)(info >> 20) * DD;
#pragma unroll
            for (int j = 0; j < 5; j++) {
                int d = lane + 64 * j;
                if (d < DD) acc[j] += hr[d] + cr[d];
            }
        }
    }
#pragma unroll
    for (int j = 0; j < 5; j++) {
        int d = lane + 64 * j;
        out[d] = (d < DD) ? f2bf(acc[j]) : (unsigned short)0;
    }
}

// ------------------------------------------- weight transpose+pad -> bf16
__global__ __launch_bounds__(256) void k_convw(const float* __restrict__ w, short* __restrict__ wt,
                                               int K, int Nn, int KP, int NP) {
    int n = blockIdx.x;
    int l = blockIdx.y;
    const float* wl = w + (size_t)l * K * Nn;
    short* wtl = wt + (size_t)l * NP * KP;
    for (int k = threadIdx.x; k < KP; k += 256) {
        float v = (k < K && n < Nn) ? wl[(size_t)k * Nn + n] : 0.f;
        wtl[(size_t)n * KP + k] = (short)f2bf(v);
    }
}

__global__ __launch_bounds__(256) void k_padb(const float* __restrict__ b, float* __restrict__ bp) {
    int l = blockIdx.y;
    int n = blockIdx.x * 256 + threadIdx.x;
    if (n < 640) bp[(size_t)l * 640 + n] = (n < DD2) ? b[(size_t)l * DD2 + n] : 0.f;
}

// ------------------------------------------- GEMM1 (MFMA bf16)
__global__ __launch_bounds__(256) void k_gemm1(const unsigned short* __restrict__ aggrb,
                                               const short* __restrict__ w1t,   // [640][320]
                                               const float* __restrict__ b1p,   // [640]
                                               unsigned short* __restrict__ hidden) {
    __shared__ short sA[2][64][40];
    __shared__ short sB[2][160][40];
    const int t  = threadIdx.x;
    const int m0 = blockIdx.x * 64;
    const int n0 = blockIdx.y * 160;
    const int ar = t >> 2, aq = (t & 3) << 3;

    {
        *(float4*)&sA[0][ar][aq] = *(const float4*)(aggrb + (size_t)(m0 + ar) * 320 + aq);
#pragma unroll
        for (int i = 0; i < 3; i++) {
            int c = t + (i << 8);
            if (c < 640) {
                int br = c >> 2, bq = (c & 3) << 3;
                *(float4*)&sB[0][br][bq] = *(const float4*)(w1t + (size_t)(n0 + br) * 320 + bq);
            }
        }
    }
    __syncthreads();

    const int lane = t & 63;
    const int w    = t >> 6;
    const int mrow = (w << 4) + (lane & 15);
    const int kb   = (lane >> 4) << 3;
    const int col  = lane & 15;
    const int rq   = (lane >> 4) << 2;

    f32x4 acc[10];
#pragma unroll
    for (int nt = 0; nt < 10; nt++) acc[nt] = (f32x4){0.f, 0.f, 0.f, 0.f};

    for (int ks = 0; ks < 10; ks++) {
        const int nb = ks & 1;
        const bool have = (ks + 1) < 10;
        float4 avr, bv0, bv1, bv2;
        if (have) {
            const int k0 = (ks + 1) << 5;
            avr = *(const float4*)(aggrb + (size_t)(m0 + ar) * 320 + k0 + aq);
            int c = t;
            bv0 = *(const float4*)(w1t + (size_t)(n0 + (c >> 2)) * 320 + k0 + ((c & 3) << 3));
            c = t + 256;
            bv1 = *(const float4*)(w1t + (size_t)(n0 + (c >> 2)) * 320 + k0 + ((c & 3) << 3));
            if (t < 128) {
                c = t + 512;
                bv2 = *(const float4*)(w1t + (size_t)(n0 + (c >> 2)) * 320 + k0 + ((c & 3) << 3));
            }
        }
        bf16x8 a = *(const bf16x8*)&sA[nb][mrow][kb];
#pragma unroll
        for (int nt = 0; nt < 10; nt++) {
            bf16x8 b = *(const bf16x8*)&sB[nb][(nt << 4) + col][kb];
            acc[nt] = __builtin_amdgcn_mfma_f32_16x16x32_bf16(a, b, acc[nt], 0, 0, 0);
        }
        if (have) {
            *(float4*)&sA[nb ^ 1][ar][aq] = avr;
            int c = t;
            *(float4*)&sB[nb ^ 1][c >> 2][(c & 3) << 3] = bv0;
            c = t + 256;
            *(float4*)&sB[nb ^ 1][c >> 2][(c & 3) << 3] = bv1;
            if (t < 128) {
                c = t + 512;
                *(float4*)&sB[nb ^ 1][c >> 2][(c & 3) << 3] = bv2;
            }
        }
        __syncthreads();
    }

#pragma unroll
    for (int nt = 0; nt < 10; nt++) {
        int n = n0 + (nt << 4) + col;
        float bias = b1p[n];
        int mbase = m0 + (w << 4) + rq;
#pragma unroll
        for (int r = 0; r < 4; r++) {
            float vz = fmaxf(acc[nt][r] + bias, 0.f);
            hidden[(size_t)(mbase + r) * 640 + n] = f2bf(vz);
        }
    }
}

// ------------------------------------------- GEMM2 (MFMA bf16)
__global__ __launch_bounds__(256) void k_gemm2(const unsigned short* __restrict__ hidden, // [Npad][640]
                                               const short* __restrict__ w2t,             // [320][640]
                                               const float* __restrict__ b2,
                                               const float* __restrict__ bng, const float* __restrict__ bnb,
                                               const float* __restrict__ bnm, const float* __restrict__ bnv,
                                               float* __restrict__ h, int N, int relu_out) {
    __shared__ short sA[2][64][40];
    __shared__ short sB[2][160][40];
    const int t  = threadIdx.x;
    const int m0 = blockIdx.x * 64;
    const int n0 = blockIdx.y * 160;
    const int ar = t >> 2, aq = (t & 3) << 3;

    {
        *(float4*)&sA[0][ar][aq] = *(const float4*)(hidden + (size_t)(m0 + ar) * 640 + aq);
#pragma unroll
        for (int i = 0; i < 3; i++) {
            int c = t + (i << 8);
            if (c < 640) {
                int br = c >> 2, bq = (c & 3) << 3;
                *(float4*)&sB[0][br][bq] = *(const float4*)(w2t + (size_t)(n0 + br) * 640 + bq);
            }
        }
    }
    __syncthreads();

    const int lane = t & 63;
    const int w    = t >> 6;
    const int mrow = (w << 4) + (lane & 15);
    const int kb   = (lane >> 4) << 3;
    const int col  = lane & 15;
    const int rq   = (lane >> 4) << 2;

    f32x4 acc[10];
#pragma unroll
    for (int nt = 0; nt < 10; nt++) acc[nt] = (f32x4){0.f, 0.f, 0.f, 0.f};

    for (int ks = 0; ks < 20; ks++) {
        const int nb = ks & 1;
        const bool have = (ks + 1) < 20;
        float4 avr, bv0, bv1, bv2;
        if (have) {
            const int k0 = (ks + 1) << 5;
            avr = *(const float4*)(hidden + (size_t)(m0 + ar) * 640 + k0 + aq);
            int c = t;
            bv0 = *(const float4*)(w2t + (size_t)(n0 + (c >> 2)) * 640 + k0 + ((c & 3) << 3));
            c = t + 256;
            bv1 = *(const float4*)(w2t + (size_t)(n0 + (c >> 2)) * 640 + k0 + ((c & 3) << 3));
            if (t < 128) {
                c = t + 512;
                bv2 = *(const float4*)(w2t + (size_t)(n0 + (c >> 2)) * 640 + k0 + ((c & 3) << 3));
            }
        }
        bf16x8 a = *(const bf16x8*)&sA[nb][mrow][kb];
#pragma unroll
        for (int nt = 0; nt < 10; nt++) {
            bf16x8 b = *(const bf16x8*)&sB[nb][(nt << 4) + col][kb];
            acc[nt] = __builtin_amdgcn_mfma_f32_16x16x32_bf16(a, b, acc[nt], 0, 0, 0);
        }
        if (have) {
            *(float4*)&sA[nb ^ 1][ar][aq] = avr;
            int c = t;
            *(float4*)&sB[nb ^ 1][c >> 2][(c & 3) << 3] = bv0;
            c = t + 256;
            *(float4*)&sB[nb ^ 1][c >> 2][(c & 3) << 3] = bv1;
            if (t < 128) {
                c = t + 512;
                *(float4*)&sB[nb ^ 1][c >> 2][(c & 3) << 3] = bv2;
            }
        }
        __syncthreads();
    }

#pragma unroll
    for (int nt = 0; nt < 10; nt++) {
        int n = n0 + (nt << 4) + col;
        bool nok = (n < DD);
        float bz = 0.f, sc = 1.f, mB = 0.f, bB = 0.f;
        if (nok) {
            bz = b2[n];
            sc = bng[n] * rsqrtf(bnv[n] + BN_EPS);
            mB = bnm[n];
            bB = bnb[n];
        }
        int mbase = m0 + (w << 4) + rq;
#pragma unroll
        for (int r = 0; r < 4; r++) {
            int m = mbase + r;
            if (nok && m < N) {
                float z = (acc[nt][r] + bz - mB) * sc + bB;
                if (relu_out) z = fmaxf(z, 0.f);
                h[(size_t)m * DD + n] = z;
            }
        }
    }
}

// ------------------------------------------- fused mean-pool + virtual-node MLP (block/graph)
// batch is sorted -> graph g owns node range [gptr[g], gptr[g+1])
__global__ __launch_bounds__(256) void k_vnpool(const float* __restrict__ h, const int* __restrict__ gptr,
                                                float* __restrict__ vnh,
                                                const float* __restrict__ w1, const float* __restrict__ b1,
                                                const float* __restrict__ lng, const float* __restrict__ lnb,
                                                const float* __restrict__ w2, const float* __restrict__ b2) {
    __shared__ float sV[DD];
    __shared__ float sT[DD];
    __shared__ float rs[4], rq[4];
    __shared__ float s_mu, s_rstd;
    int g = blockIdx.x, t = threadIdx.x;
    const int gs = gptr[g], ge = gptr[g + 1];
    const float inv = 1.0f / fmaxf((float)(ge - gs), 1.0f);

    const int j0 = t, j1 = t + 256;     // j0 < 256 < DD always
    const bool g1 = (j1 < DD);

    // mean-pool this graph's node range (coalesced across threads)
    float a0 = 0.f, a1 = 0.f;
    for (int n = gs; n < ge; n++) {
        a0 += h[(size_t)n * DD + j0];
        if (g1) a1 += h[(size_t)n * DD + j1];
    }
    sV[j0] = a0 * inv + vnh[(size_t)g * DD + j0];
    if (g1) sV[j1] = a1 * inv + vnh[(size_t)g * DD + j1];
    __syncthreads();

    // t = vn_new @ W1 + b1
    a0 = 0.f; a1 = 0.f;
    for (int k = 0; k < DD; k++) {
        float v = sV[k];
        const float* wr = w1 + (size_t)k * DD;
        a0 = fmaf(v, wr[j0], a0);
        a1 = fmaf(v, g1 ? wr[j1] : 0.f, a1);
    }
    float t0 = a0 + b1[j0];
    float t1 = g1 ? (a1 + b1[j1]) : 0.f;
    sT[j0] = t0;
    if (g1) sT[j1] = t1;
    __syncthreads();

    // LayerNorm stats
    float ps = 0.f, pq = 0.f;
    for (int i = t; i < DD; i += 256) { float x = sT[i]; ps += x; pq += x * x; }
    for (int off = 32; off >= 1; off >>= 1) { ps += __shfl_down(ps, off, 64); pq += __shfl_down(pq, off, 64); }
    int wid = t >> 6, lane = t & 63;
    if (lane == 0) { rs[wid] = ps; rq[wid] = pq; }
    __syncthreads();
    if (t == 0) {
        float S = rs[0] + rs[1] + rs[2] + rs[3];
        float Q = rq[0] + rq[1] + rq[2] + rq[3];
        float mu = S / DD;
        float var = Q / DD - mu * mu;
        s_mu = mu;
        s_rstd = rsqrtf(var + BN_EPS);
    }
    __syncthreads();
    float mu = s_mu, rstd = s_rstd;
    float r0 = fmaxf((t0 - mu) * rstd * lng[j0] + lnb[j0], 0.f);
    float r1 = g1 ? fmaxf((t1 - mu) * rstd * lng[j1] + lnb[j1], 0.f) : 0.f;
    sT[j0] = r0;
    if (g1) sT[j1] = r1;
    __syncthreads();

    // vn_h = relu(t) @ W2 + b2
    float o0 = 0.f, o1 = 0.f;
    for (int k = 0; k < DD; k++) {
        float v = sT[k];
        const float* wr = w2 + (size_t)k * DD;
        o0 = fmaf(v, wr[j0], o0);
        o1 = fmaf(v, g1 ? wr[j1] : 0.f, o1);
    }
    vnh[(size_t)g * DD + j0] = o0 + b2[j0];
    if (g1) vnh[(size_t)g * DD + j1] = o1 + b2[j1];
}

extern "C" void kernel_launch(void* const* d_in, const int* in_sizes, int n_in,
                              void* d_out, int out_size, void* d_ws, size_t ws_size,
                              hipStream_t stream) {
    const int*   x_atom = (const int*)d_in[0];
    const int*   x_chir = (const int*)d_in[1];
    const int*   src    = (const int*)d_in[2];
    const int*   dst    = (const int*)d_in[3];
    const int*   ety    = (const int*)d_in[4];
    const int*   edir   = (const int*)d_in[5];
    const int*   batch  = (const int*)d_in[6];
    const float* emb1   = (const float*)d_in[7];
    const float* emb2   = (const float*)d_in[8];
    const float* e1     = (const float*)d_in[9];
    const float* e2     = (const float*)d_in[10];
    const float* w1     = (const float*)d_in[11];
    const float* b1     = (const float*)d_in[12];
    const float* w2     = (const float*)d_in[13];
    const float* b2     = (const float*)d_in[14];
    const float* bng    = (const float*)d_in[15];
    const float* bnb    = (const float*)d_in[16];
    const float* bnm    = (const float*)d_in[17];
    const float* bnv    = (const float*)d_in[18];
    const float* vne    = (const float*)d_in[19];
    const float* vw1    = (const float*)d_in[20];
    const float* vb1    = (const float*)d_in[21];
    const float* lng    = (const float*)d_in[22];
    const float* lnb    = (const float*)d_in[23];
    const float* vw2    = (const float*)d_in[24];
    const float* vb2    = (const float*)d_in[25];

    const int N = in_sizes[0];
    const int E = in_sizes[2];
    const int gx = (N + 63) / 64;
    const int Npad = gx * 64;
    const int nbN = (N + 255) / 256;     // blocks for N-scan (<=1024)
    const int nbG = (GG + 255) / 256;    // blocks for G-scan

    float* h = (float*)d_out;                                   // [N, D]

    // workspace layout
    unsigned short* aggrb  = (unsigned short*)d_ws;                      // [Npad,320] bf16
    unsigned short* hidden = aggrb + (size_t)Npad * 320;                 // [Npad,640] bf16
    short*          w1t    = (short*)(hidden + (size_t)Npad * 640);      // [L,640,320] bf16
    short*          w2t    = w1t + (size_t)LL * 640 * 320;               // [L,320,640] bf16
    float*          b1p    = (float*)(w2t + (size_t)LL * 320 * 640);     // [L,640]
    float*          comb   = b1p + (size_t)LL * 640;                     // [L,18,300]
    float*          vnh    = comb + (size_t)LL * 18 * DD;                // [G,300]
    int*            deg    = (int*)(vnh + (size_t)GG * DD);              // [N]      } zeroed
    int*            cursor = deg + N;                                    // [N]      } as one
    int*            gcnt   = cursor + N;                                 // [G]      } memset
    int*            rowptr = gcnt + GG;                                  // [N+1]
    int*            gptr   = rowptr + (N + 1);                           // [G+1]
    int*            bsumN  = gptr + (GG + 1);                            // [nbN]
    int*            bsumG  = bsumN + 1024;                               // [nbG]
    int*            einfo  = bsumG + 1024;                               // [E]

    // --- weight prep ---
    k_convw<<<dim3(640, LL), 256, 0, stream>>>(w1, w1t, DD, DD2, 320, 640);
    k_convw<<<dim3(320, LL), 256, 0, stream>>>(w2, w2t, DD2, DD, 640, 320);
    k_padb<<<dim3(3, LL), 256, 0, stream>>>(b1, b1p);
    k_comb<<<dim3(18, LL), 256, 0, stream>>>(e1, e2, comb);

    // --- CSR (by dst) + graph ranges (batch sorted) ---
    hipMemsetAsync(deg, 0, (size_t)(2 * N + GG) * sizeof(int), stream);
    k_hist<<<(E + 255) / 256, 256, 0, stream>>>(dst, deg, E);
    k_hist<<<(N + 255) / 256, 256, 0, stream>>>(batch, gcnt, N);
    k_scan1<<<nbN, 256, 0, stream>>>(deg, bsumN, N);
    k_scan2<<<1, 1024, 0, stream>>>(bsumN, nbN);
    k_scan3<<<nbN, 256, 0, stream>>>(deg, bsumN, rowptr, N, E);
    k_scan1<<<nbG, 256, 0, stream>>>(gcnt, bsumG, GG);
    k_scan2<<<1, 1024, 0, stream>>>(bsumG, nbG);
    k_scan3<<<nbG, 256, 0, stream>>>(gcnt, bsumG, gptr, GG, N);
    k_place<<<(E + 255) / 256, 256, 0, stream>>>(src, dst, ety, edir, rowptr, cursor, einfo, E);

    k_init_h<<<N, 256, 0, stream>>>(x_atom, x_chir, emb1, emb2, vne, h, N);
    k_init_vn<<<GG, 256, 0, stream>>>(vne, vnh);

    for (int l = 0; l < LL; l++) {
        k_aggr<<<Npad / 4, 256, 0, stream>>>(h, rowptr, einfo, comb + (size_t)l * 18 * DD,
                                             batch, vnh, (l > 0) ? 1 : 0, aggrb, N, Npad);
        k_gemm1<<<dim3(gx, 4), 256, 0, stream>>>(aggrb, w1t + (size_t)l * 640 * 320,
                                                 b1p + (size_t)l * 640, hidden);
        k_gemm2<<<dim3(gx, 2), 256, 0, stream>>>(hidden, w2t + (size_t)l * 320 * 640,
                                                 b2 + (size_t)l * DD,
                                                 bng + (size_t)l * DD, bnb + (size_t)l * DD,
                                                 bnm + (size_t)l * DD, bnv + (size_t)l * DD,
                                                 h, N, (l < LL - 1) ? 1 : 0);
        if (l < LL - 1) {
            k_vnpool<<<GG, 256, 0, stream>>>(h, gptr, vnh,
                                             vw1 + (size_t)l * DD * DD, vb1 + (size_t)l * DD,
                                             lng + (size_t)l * DD, lnb + (size_t)l * DD,
                                             vw2 + (size_t)l * DD * DD, vb2 + (size_t)l * DD);
        }
    }
}

// Round 5
// 2180.628 us; speedup vs baseline: 5.0259x; 1.1449x over previous
//
#include <hip/hip_runtime.h>

// Problem constants (fixed by the reference)
#define DD   300     // emb dim
#define DD2  600     // 2*D
#define GG   4000    // graphs
#define GPAD 4096    // padded graph count (multiple of 64)
#define LL   5       // layers
#define BN_EPS 1e-5f

typedef float f32x4  __attribute__((ext_vector_type(4)));
typedef short bf16x8 __attribute__((ext_vector_type(8)));

__device__ __forceinline__ unsigned short f2bf(float f) {
    unsigned int x = __float_as_uint(f);
    unsigned int r = (x + 0x7FFFu + ((x >> 16) & 1u)) >> 16;   // RTNE
    return (unsigned short)r;
}

// ---------------------------------------------------------------- histogram
__global__ __launch_bounds__(256) void k_hist(const int* __restrict__ idx, int* __restrict__ cnt, int n) {
    int i = blockIdx.x * 256 + threadIdx.x;
    if (i < n) atomicAdd(&cnt[idx[i]], 1);
}

// ---------------------------------------------------------------- hierarchical exclusive scan
__global__ __launch_bounds__(256) void k_scan1(const int* __restrict__ in, int* __restrict__ bsum, int n) {
    int t = threadIdx.x;
    int i = blockIdx.x * 256 + t;
    int v = (i < n) ? in[i] : 0;
    for (int off = 32; off >= 1; off >>= 1) v += __shfl_down(v, off, 64);
    __shared__ int s[4];
    if ((t & 63) == 0) s[t >> 6] = v;
    __syncthreads();
    if (t == 0) bsum[blockIdx.x] = s[0] + s[1] + s[2] + s[3];
}
__global__ __launch_bounds__(1024) void k_scan2(int* __restrict__ bsum, int nb) {
    __shared__ int s[1024];
    int t = threadIdx.x;
    int v = (t < nb) ? bsum[t] : 0;
    s[t] = v;
    __syncthreads();
    for (int off = 1; off < 1024; off <<= 1) {
        int u = (t >= off) ? s[t - off] : 0;
        __syncthreads();
        s[t] += u;
        __syncthreads();
    }
    if (t < nb) bsum[t] = s[t] - v;   // exclusive
}
__global__ __launch_bounds__(256) void k_scan3(const int* __restrict__ in, const int* __restrict__ boff,
                                               int* __restrict__ out, int n, int total) {
    __shared__ int s[256];
    int t = threadIdx.x;
    int i = blockIdx.x * 256 + t;
    int v = (i < n) ? in[i] : 0;
    s[t] = v;
    __syncthreads();
    for (int off = 1; off < 256; off <<= 1) {
        int u = (t >= off) ? s[t - off] : 0;
        __syncthreads();
        s[t] += u;
        __syncthreads();
    }
    if (i < n) out[i] = boff[blockIdx.x] + s[t] - v;
    if (i == 0) out[n] = total;
}

// place edges grouped by dst; einfo = src | (code<<20), code = type*3+dir
__global__ __launch_bounds__(256) void k_place(const int* __restrict__ src, const int* __restrict__ dst,
                                               const int* __restrict__ ety, const int* __restrict__ edir,
                                               const int* __restrict__ rowptr, int* __restrict__ cursor,
                                               int* __restrict__ einfo, int E) {
    int e = blockIdx.x * 256 + threadIdx.x;
    if (e >= E) return;
    int d = dst[e];
    int pos = rowptr[d] + atomicAdd(&cursor[d], 1);
    einfo[pos] = src[e] | ((ety[e] * 3 + edir[e]) << 20);
}

// ---------------------------------------------------------------- comb tables
__global__ __launch_bounds__(256) void k_comb(const float* __restrict__ e1, const float* __restrict__ e2,
                                              float* __restrict__ comb) {
    int c = blockIdx.x, l = blockIdx.y;
    const float* r1 = e1 + ((size_t)l * 6 + (c / 3)) * DD;
    const float* r2 = e2 + ((size_t)l * 3 + (c % 3)) * DD;
    float* out = comb + ((size_t)l * 18 + c) * DD;
    for (int d = threadIdx.x; d < DD; d += 256) out[d] = r1[d] + r2[d];
}

// ---------------------------------------------------------------- h init
__global__ __launch_bounds__(256) void k_init_h(const int* __restrict__ xa, const int* __restrict__ xc,
                                                const float* __restrict__ emb1, const float* __restrict__ emb2,
                                                const float* __restrict__ vne,
                                                float* __restrict__ h, int N) {
    int n = blockIdx.x;
    if (n >= N) return;
    int a = xa[n], c = xc[n];
    for (int d = threadIdx.x; d < DD; d += 256)
        h[(size_t)n * DD + d] = emb1[(size_t)a * DD + d] + emb2[(size_t)c * DD + d] + vne[d];
}

__global__ __launch_bounds__(256) void k_init_vn(const float* __restrict__ vne, float* __restrict__ vnh) {
    int g = blockIdx.x;
    for (int d = threadIdx.x; d < DD; d += 256) vnh[(size_t)g * DD + d] = vne[d];
}

// ---------------------------------------------------------------- fused aggregation (CSR gather)
__global__ __launch_bounds__(256) void k_aggr(const float* __restrict__ h,
                                              const int* __restrict__ rowptr, const int* __restrict__ einfo,
                                              const float* __restrict__ comb,
                                              const int* __restrict__ batch, const float* __restrict__ vnh,
                                              int use_vn,
                                              unsigned short* __restrict__ aggrb, int N, int Npad) {
    const int node = blockIdx.x * 4 + (threadIdx.x >> 6);
    const int lane = threadIdx.x & 63;
    if (node >= Npad) return;
    unsigned short* out = aggrb + (size_t)node * 320;
    if (node >= N) {
#pragma unroll
        for (int j = 0; j < 5; j++) out[lane + 64 * j] = 0;
        return;
    }
    float acc[5];
    const float* sc = comb + 12 * DD;   // self-loop: type 4, dir 0
    const int p0 = rowptr[node], p1 = rowptr[node + 1];
    if (use_vn) {
        {
            const float* hs = h + (size_t)node * DD;
            const float* vs = vnh + (size_t)batch[node] * DD;
#pragma unroll
            for (int j = 0; j < 5; j++) {
                int d = lane + 64 * j;
                acc[j] = (d < DD) ? hs[d] + sc[d] + vs[d] : 0.f;
            }
        }
        for (int p = p0; p < p1; p++) {
            int info = einfo[p];
            int s = info & 0xFFFFF;
            const float* hr = h + (size_t)s * DD;
            const float* cr = comb + (size_t)(info >> 20) * DD;
            const float* vr = vnh + (size_t)batch[s] * DD;
#pragma unroll
            for (int j = 0; j < 5; j++) {
                int d = lane + 64 * j;
                if (d < DD) acc[j] += hr[d] + cr[d] + vr[d];
            }
        }
    } else {
        {
            const float* hs = h + (size_t)node * DD;
#pragma unroll
            for (int j = 0; j < 5; j++) {
                int d = lane + 64 * j;
                acc[j] = (d < DD) ? hs[d] + sc[d] : 0.f;
            }
        }
        for (int p = p0; p < p1; p++) {
            int info = einfo[p];
            const float* hr = h + (size_t)(info & 0xFFFFF) * DD;
            const float* cr = comb + (size_t)(info >> 20) * DD;
#pragma unroll
            for (int j = 0; j < 5; j++) {
                int d = lane + 64 * j;
                if (d < DD) acc[j] += hr[d] + cr[d];
            }
        }
    }
#pragma unroll
    for (int j = 0; j < 5; j++) {
        int d = lane + 64 * j;
        out[d] = (d < DD) ? f2bf(acc[j]) : (unsigned short)0;
    }
}

// ------------------------------------------- weight transpose+pad -> bf16
__global__ __launch_bounds__(256) void k_convw(const float* __restrict__ w, short* __restrict__ wt,
                                               int K, int Nn, int KP, int NP) {
    int n = blockIdx.x;
    int l = blockIdx.y;
    const float* wl = w + (size_t)l * K * Nn;
    short* wtl = wt + (size_t)l * NP * KP;
    for (int k = threadIdx.x; k < KP; k += 256) {
        float v = (k < K && n < Nn) ? wl[(size_t)k * Nn + n] : 0.f;
        wtl[(size_t)n * KP + k] = (short)f2bf(v);
    }
}

__global__ __launch_bounds__(256) void k_padb(const float* __restrict__ b, float* __restrict__ bp) {
    int l = blockIdx.y;
    int n = blockIdx.x * 256 + threadIdx.x;
    if (n < 640) bp[(size_t)l * 640 + n] = (n < DD2) ? b[(size_t)l * DD2 + n] : 0.f;
}

// ------------------------------------------- GEMM1 (MFMA bf16): hidden = relu(aggrb @ W1t^T + b1)
__global__ __launch_bounds__(256) void k_gemm1(const unsigned short* __restrict__ aggrb,
                                               const short* __restrict__ w1t,   // [640][320]
                                               const float* __restrict__ b1p,   // [640]
                                               unsigned short* __restrict__ hidden) {
    __shared__ short sA[2][64][40];
    __shared__ short sB[2][160][40];
    const int t  = threadIdx.x;
    const int m0 = blockIdx.x * 64;
    const int n0 = blockIdx.y * 160;
    const int ar = t >> 2, aq = (t & 3) << 3;

    {
        *(float4*)&sA[0][ar][aq] = *(const float4*)(aggrb + (size_t)(m0 + ar) * 320 + aq);
#pragma unroll
        for (int i = 0; i < 3; i++) {
            int c = t + (i << 8);
            if (c < 640) {
                int br = c >> 2, bq = (c & 3) << 3;
                *(float4*)&sB[0][br][bq] = *(const float4*)(w1t + (size_t)(n0 + br) * 320 + bq);
            }
        }
    }
    __syncthreads();

    const int lane = t & 63;
    const int w    = t >> 6;
    const int mrow = (w << 4) + (lane & 15);
    const int kb   = (lane >> 4) << 3;
    const int col  = lane & 15;
    const int rq   = (lane >> 4) << 2;

    f32x4 acc[10];
#pragma unroll
    for (int nt = 0; nt < 10; nt++) acc[nt] = (f32x4){0.f, 0.f, 0.f, 0.f};

    for (int ks = 0; ks < 10; ks++) {
        const int nb = ks & 1;
        const bool have = (ks + 1) < 10;
        float4 avr, bv0, bv1, bv2;
        if (have) {
            const int k0 = (ks + 1) << 5;
            avr = *(const float4*)(aggrb + (size_t)(m0 + ar) * 320 + k0 + aq);
            int c = t;
            bv0 = *(const float4*)(w1t + (size_t)(n0 + (c >> 2)) * 320 + k0 + ((c & 3) << 3));
            c = t + 256;
            bv1 = *(const float4*)(w1t + (size_t)(n0 + (c >> 2)) * 320 + k0 + ((c & 3) << 3));
            if (t < 128) {
                c = t + 512;
                bv2 = *(const float4*)(w1t + (size_t)(n0 + (c >> 2)) * 320 + k0 + ((c & 3) << 3));
            }
        }
        bf16x8 a = *(const bf16x8*)&sA[nb][mrow][kb];
#pragma unroll
        for (int nt = 0; nt < 10; nt++) {
            bf16x8 b = *(const bf16x8*)&sB[nb][(nt << 4) + col][kb];
            acc[nt] = __builtin_amdgcn_mfma_f32_16x16x32_bf16(a, b, acc[nt], 0, 0, 0);
        }
        if (have) {
            *(float4*)&sA[nb ^ 1][ar][aq] = avr;
            int c = t;
            *(float4*)&sB[nb ^ 1][c >> 2][(c & 3) << 3] = bv0;
            c = t + 256;
            *(float4*)&sB[nb ^ 1][c >> 2][(c & 3) << 3] = bv1;
            if (t < 128) {
                c = t + 512;
                *(float4*)&sB[nb ^ 1][c >> 2][(c & 3) << 3] = bv2;
            }
        }
        __syncthreads();
    }

#pragma unroll
    for (int nt = 0; nt < 10; nt++) {
        int n = n0 + (nt << 4) + col;
        float bias = b1p[n];
        int mbase = m0 + (w << 4) + rq;
#pragma unroll
        for (int r = 0; r < 4; r++) {
            float vz = fmaxf(acc[nt][r] + bias, 0.f);
            hidden[(size_t)(mbase + r) * 640 + n] = f2bf(vz);
        }
    }
}

// ------------------------------------------- GEMM2 (MFMA bf16): h = BN(hidden @ W2t^T + b2)(+ReLU)
__global__ __launch_bounds__(256) void k_gemm2(const unsigned short* __restrict__ hidden, // [Npad][640]
                                               const short* __restrict__ w2t,             // [320][640]
                                               const float* __restrict__ b2,
                                               const float* __restrict__ bng, const float* __restrict__ bnb,
                                               const float* __restrict__ bnm, const float* __restrict__ bnv,
                                               float* __restrict__ h, int N, int relu_out) {
    __shared__ short sA[2][64][40];
    __shared__ short sB[2][160][40];
    const int t  = threadIdx.x;
    const int m0 = blockIdx.x * 64;
    const int n0 = blockIdx.y * 160;
    const int ar = t >> 2, aq = (t & 3) << 3;

    {
        *(float4*)&sA[0][ar][aq] = *(const float4*)(hidden + (size_t)(m0 + ar) * 640 + aq);
#pragma unroll
        for (int i = 0; i < 3; i++) {
            int c = t + (i << 8);
            if (c < 640) {
                int br = c >> 2, bq = (c & 3) << 3;
                *(float4*)&sB[0][br][bq] = *(const float4*)(w2t + (size_t)(n0 + br) * 640 + bq);
            }
        }
    }
    __syncthreads();

    const int lane = t & 63;
    const int w    = t >> 6;
    const int mrow = (w << 4) + (lane & 15);
    const int kb   = (lane >> 4) << 3;
    const int col  = lane & 15;
    const int rq   = (lane >> 4) << 2;

    f32x4 acc[10];
#pragma unroll
    for (int nt = 0; nt < 10; nt++) acc[nt] = (f32x4){0.f, 0.f, 0.f, 0.f};

    for (int ks = 0; ks < 20; ks++) {
        const int nb = ks & 1;
        const bool have = (ks + 1) < 20;
        float4 avr, bv0, bv1, bv2;
        if (have) {
            const int k0 = (ks + 1) << 5;
            avr = *(const float4*)(hidden + (size_t)(m0 + ar) * 640 + k0 + aq);
            int c = t;
            bv0 = *(const float4*)(w2t + (size_t)(n0 + (c >> 2)) * 640 + k0 + ((c & 3) << 3));
            c = t + 256;
            bv1 = *(const float4*)(w2t + (size_t)(n0 + (c >> 2)) * 640 + k0 + ((c & 3) << 3));
            if (t < 128) {
                c = t + 512;
                bv2 = *(const float4*)(w2t + (size_t)(n0 + (c >> 2)) * 640 + k0 + ((c & 3) << 3));
            }
        }
        bf16x8 a = *(const bf16x8*)&sA[nb][mrow][kb];
#pragma unroll
        for (int nt = 0; nt < 10; nt++) {
            bf16x8 b = *(const bf16x8*)&sB[nb][(nt << 4) + col][kb];
            acc[nt] = __builtin_amdgcn_mfma_f32_16x16x32_bf16(a, b, acc[nt], 0, 0, 0);
        }
        if (have) {
            *(float4*)&sA[nb ^ 1][ar][aq] = avr;
            int c = t;
            *(float4*)&sB[nb ^ 1][c >> 2][(c & 3) << 3] = bv0;
            c = t + 256;
            *(float4*)&sB[nb ^ 1][c >> 2][(c & 3) << 3] = bv1;
            if (t < 128) {
                c = t + 512;
                *(float4*)&sB[nb ^ 1][c >> 2][(c & 3) << 3] = bv2;
            }
        }
        __syncthreads();
    }

#pragma unroll
    for (int nt = 0; nt < 10; nt++) {
        int n = n0 + (nt << 4) + col;
        bool nok = (n < DD);
        float bz = 0.f, sc = 1.f, mB = 0.f, bB = 0.f;
        if (nok) {
            bz = b2[n];
            sc = bng[n] * rsqrtf(bnv[n] + BN_EPS);
            mB = bnm[n];
            bB = bnb[n];
        }
        int mbase = m0 + (w << 4) + rq;
#pragma unroll
        for (int r = 0; r < 4; r++) {
            int m = mbase + r;
            if (nok && m < N) {
                float z = (acc[nt][r] + bz - mB) * sc + bB;
                if (relu_out) z = fmaxf(z, 0.f);
                h[(size_t)m * DD + n] = z;
            }
        }
    }
}

// ------------------------------------------- mean-pool + vnh add -> bf16 vnin[G][320]
__global__ __launch_bounds__(256) void k_pool2(const float* __restrict__ h, const int* __restrict__ gptr,
                                               const float* __restrict__ vnh,
                                               unsigned short* __restrict__ vnin) {
    int g = blockIdx.x, t = threadIdx.x;
    const int gs = gptr[g], ge = gptr[g + 1];
    const float inv = 1.0f / fmaxf((float)(ge - gs), 1.0f);
    const int j0 = t, j1 = t + 256;
    const bool g1 = (j1 < DD);
    float a0 = 0.f, a1 = 0.f;
    for (int n = gs; n < ge; n++) {
        a0 += h[(size_t)n * DD + j0];
        if (g1) a1 += h[(size_t)n * DD + j1];
    }
    vnin[(size_t)g * 320 + j0] = f2bf(a0 * inv + vnh[(size_t)g * DD + j0]);
    if (j1 < 320)
        vnin[(size_t)g * 320 + j1] = g1 ? f2bf(a1 * inv + vnh[(size_t)g * DD + j1]) : (unsigned short)0;
}

// ------------------------------------------- VN GEMM (MFMA bf16), M=GPAD, N=320, K=320
// mode 0: out_f32[m*300+n] = acc + bias[n]            (t = vn_new@W1 + b1)
// mode 1: out_f32[m*300+n] = acc + bias[n]            (vnh = relu(t)@W2 + b2)  [same math, diff buffers]
__global__ __launch_bounds__(256) void k_vng(const unsigned short* __restrict__ A,   // [GPAD][320] bf16
                                             const short* __restrict__ Wt,           // [320][320] bf16
                                             const float* __restrict__ bias,         // [300]
                                             float* __restrict__ outf,               // [G][300] f32
                                             int M) {
    __shared__ short sA[2][64][40];
    __shared__ short sB[2][160][40];
    const int t  = threadIdx.x;
    const int m0 = blockIdx.x * 64;
    const int n0 = blockIdx.y * 160;
    const int ar = t >> 2, aq = (t & 3) << 3;

    {
        *(float4*)&sA[0][ar][aq] = *(const float4*)(A + (size_t)(m0 + ar) * 320 + aq);
#pragma unroll
        for (int i = 0; i < 3; i++) {
            int c = t + (i << 8);
            if (c < 640) {
                int br = c >> 2, bq = (c & 3) << 3;
                *(float4*)&sB[0][br][bq] = *(const float4*)(Wt + (size_t)(n0 + br) * 320 + bq);
            }
        }
    }
    __syncthreads();

    const int lane = t & 63;
    const int w    = t >> 6;
    const int mrow = (w << 4) + (lane & 15);
    const int kb   = (lane >> 4) << 3;
    const int col  = lane & 15;
    const int rq   = (lane >> 4) << 2;

    f32x4 acc[10];
#pragma unroll
    for (int nt = 0; nt < 10; nt++) acc[nt] = (f32x4){0.f, 0.f, 0.f, 0.f};

    for (int ks = 0; ks < 10; ks++) {
        const int nb = ks & 1;
        const bool have = (ks + 1) < 10;
        float4 avr, bv0, bv1, bv2;
        if (have) {
            const int k0 = (ks + 1) << 5;
            avr = *(const float4*)(A + (size_t)(m0 + ar) * 320 + k0 + aq);
            int c = t;
            bv0 = *(const float4*)(Wt + (size_t)(n0 + (c >> 2)) * 320 + k0 + ((c & 3) << 3));
            c = t + 256;
            bv1 = *(const float4*)(Wt + (size_t)(n0 + (c >> 2)) * 320 + k0 + ((c & 3) << 3));
            if (t < 128) {
                c = t + 512;
                bv2 = *(const float4*)(Wt + (size_t)(n0 + (c >> 2)) * 320 + k0 + ((c & 3) << 3));
            }
        }
        bf16x8 a = *(const bf16x8*)&sA[nb][mrow][kb];
#pragma unroll
        for (int nt = 0; nt < 10; nt++) {
            bf16x8 b = *(const bf16x8*)&sB[nb][(nt << 4) + col][kb];
            acc[nt] = __builtin_amdgcn_mfma_f32_16x16x32_bf16(a, b, acc[nt], 0, 0, 0);
        }
        if (have) {
            *(float4*)&sA[nb ^ 1][ar][aq] = avr;
            int c = t;
            *(float4*)&sB[nb ^ 1][c >> 2][(c & 3) << 3] = bv0;
            c = t + 256;
            *(float4*)&sB[nb ^ 1][c >> 2][(c & 3) << 3] = bv1;
            if (t < 128) {
                c = t + 512;
                *(float4*)&sB[nb ^ 1][c >> 2][(c & 3) << 3] = bv2;
            }
        }
        __syncthreads();
    }

#pragma unroll
    for (int nt = 0; nt < 10; nt++) {
        int n = n0 + (nt << 4) + col;
        bool nok = (n < DD);
        float bz = nok ? bias[n] : 0.f;
        int mbase = m0 + (w << 4) + rq;
#pragma unroll
        for (int r = 0; r < 4; r++) {
            int m = mbase + r;
            if (nok && m < M)
                outf[(size_t)m * DD + n] = acc[nt][r] + bz;
        }
    }
}

// ------------------------------------------- row LayerNorm + ReLU -> bf16 [G][320]
__global__ __launch_bounds__(256) void k_ln(const float* __restrict__ tbuf,   // [G][300]
                                            const float* __restrict__ lng, const float* __restrict__ lnb,
                                            unsigned short* __restrict__ vnrelu) {
    __shared__ float rs[4], rq[4];
    __shared__ float s_mu, s_rstd;
    int g = blockIdx.x, t = threadIdx.x;
    const int j0 = t, j1 = t + 256;
    const bool g1 = (j1 < DD);
    float t0 = tbuf[(size_t)g * DD + j0];
    float t1 = g1 ? tbuf[(size_t)g * DD + j1] : 0.f;
    float ps = t0 + t1;
    float pq = t0 * t0 + t1 * t1;
    for (int off = 32; off >= 1; off >>= 1) { ps += __shfl_down(ps, off, 64); pq += __shfl_down(pq, off, 64); }
    int wid = t >> 6, lane = t & 63;
    if (lane == 0) { rs[wid] = ps; rq[wid] = pq; }
    __syncthreads();
    if (t == 0) {
        float S = rs[0] + rs[1] + rs[2] + rs[3];
        float Q = rq[0] + rq[1] + rq[2] + rq[3];
        float mu = S / DD;
        float var = Q / DD - mu * mu;
        s_mu = mu;
        s_rstd = rsqrtf(var + BN_EPS);
    }
    __syncthreads();
    float mu = s_mu, rstd = s_rstd;
    float r0 = fmaxf((t0 - mu) * rstd * lng[j0] + lnb[j0], 0.f);
    vnrelu[(size_t)g * 320 + j0] = f2bf(r0);
    if (j1 < 320) {
        float r1 = g1 ? fmaxf((t1 - mu) * rstd * lng[j1] + lnb[j1], 0.f) : 0.f;
        vnrelu[(size_t)g * 320 + j1] = g1 ? f2bf(r1) : (unsigned short)0;
    }
}

extern "C" void kernel_launch(void* const* d_in, const int* in_sizes, int n_in,
                              void* d_out, int out_size, void* d_ws, size_t ws_size,
                              hipStream_t stream) {
    const int*   x_atom = (const int*)d_in[0];
    const int*   x_chir = (const int*)d_in[1];
    const int*   src    = (const int*)d_in[2];
    const int*   dst    = (const int*)d_in[3];
    const int*   ety    = (const int*)d_in[4];
    const int*   edir   = (const int*)d_in[5];
    const int*   batch  = (const int*)d_in[6];
    const float* emb1   = (const float*)d_in[7];
    const float* emb2   = (const float*)d_in[8];
    const float* e1     = (const float*)d_in[9];
    const float* e2     = (const float*)d_in[10];
    const float* w1     = (const float*)d_in[11];
    const float* b1     = (const float*)d_in[12];
    const float* w2     = (const float*)d_in[13];
    const float* b2     = (const float*)d_in[14];
    const float* bng    = (const float*)d_in[15];
    const float* bnb    = (const float*)d_in[16];
    const float* bnm    = (const float*)d_in[17];
    const float* bnv    = (const float*)d_in[18];
    const float* vne    = (const float*)d_in[19];
    const float* vw1    = (const float*)d_in[20];
    const float* vb1    = (const float*)d_in[21];
    const float* lng    = (const float*)d_in[22];
    const float* lnb    = (const float*)d_in[23];
    const float* vw2    = (const float*)d_in[24];
    const float* vb2    = (const float*)d_in[25];

    const int N = in_sizes[0];
    const int E = in_sizes[2];
    const int gx = (N + 63) / 64;
    const int Npad = gx * 64;
    const int nbN = (N + 255) / 256;
    const int nbG = (GG + 255) / 256;

    float* h = (float*)d_out;                                   // [N, D]

    // workspace layout
    unsigned short* aggrb  = (unsigned short*)d_ws;                      // [Npad,320] bf16
    unsigned short* hidden = aggrb + (size_t)Npad * 320;                 // [Npad,640] bf16
    short*          w1t    = (short*)(hidden + (size_t)Npad * 640);      // [L,640,320] bf16
    short*          w2t    = w1t + (size_t)LL * 640 * 320;               // [L,320,640] bf16
    short*          vw1t   = w2t + (size_t)LL * 320 * 640;               // [L-1,320,320] bf16
    short*          vw2t   = vw1t + (size_t)(LL - 1) * 320 * 320;        // [L-1,320,320] bf16
    unsigned short* vnin   = (unsigned short*)(vw2t + (size_t)(LL - 1) * 320 * 320); // [GPAD,320] bf16
    unsigned short* vnrelu = vnin + (size_t)GPAD * 320;                  // [GPAD,320] bf16
    float*          b1p    = (float*)(vnrelu + (size_t)GPAD * 320);      // [L,640]
    float*          comb   = b1p + (size_t)LL * 640;                     // [L,18,300]
    float*          tbuf   = comb + (size_t)LL * 18 * DD;                // [G,300]
    float*          vnh    = tbuf + (size_t)GG * DD;                     // [G,300]
    int*            deg    = (int*)(vnh + (size_t)GG * DD);              // [N]      } zeroed
    int*            cursor = deg + N;                                    // [N]      } as one
    int*            gcnt   = cursor + N;                                 // [G]      } memset
    int*            rowptr = gcnt + GG;                                  // [N+1]
    int*            gptr   = rowptr + (N + 1);                           // [G+1]
    int*            bsumN  = gptr + (GG + 1);                            // [nbN]
    int*            bsumG  = bsumN + 1024;                               // [nbG]
    int*            einfo  = bsumG + 1024;                               // [E]

    // --- weight prep ---
    k_convw<<<dim3(640, LL), 256, 0, stream>>>(w1, w1t, DD, DD2, 320, 640);
    k_convw<<<dim3(320, LL), 256, 0, stream>>>(w2, w2t, DD2, DD, 640, 320);
    k_convw<<<dim3(320, LL - 1), 256, 0, stream>>>(vw1, vw1t, DD, DD, 320, 320);
    k_convw<<<dim3(320, LL - 1), 256, 0, stream>>>(vw2, vw2t, DD, DD, 320, 320);
    k_padb<<<dim3(3, LL), 256, 0, stream>>>(b1, b1p);
    k_comb<<<dim3(18, LL), 256, 0, stream>>>(e1, e2, comb);

    // --- CSR (by dst) + graph ranges (batch sorted) ---
    hipMemsetAsync(deg, 0, (size_t)(2 * N + GG) * sizeof(int), stream);
    k_hist<<<(E + 255) / 256, 256, 0, stream>>>(dst, deg, E);
    k_hist<<<(N + 255) / 256, 256, 0, stream>>>(batch, gcnt, N);
    k_scan1<<<nbN, 256, 0, stream>>>(deg, bsumN, N);
    k_scan2<<<1, 1024, 0, stream>>>(bsumN, nbN);
    k_scan3<<<nbN, 256, 0, stream>>>(deg, bsumN, rowptr, N, E);
    k_scan1<<<nbG, 256, 0, stream>>>(gcnt, bsumG, GG);
    k_scan2<<<1, 1024, 0, stream>>>(bsumG, nbG);
    k_scan3<<<nbG, 256, 0, stream>>>(gcnt, bsumG, gptr, GG, N);
    k_place<<<(E + 255) / 256, 256, 0, stream>>>(src, dst, ety, edir, rowptr, cursor, einfo, E);

    k_init_h<<<N, 256, 0, stream>>>(x_atom, x_chir, emb1, emb2, vne, h, N);
    k_init_vn<<<GG, 256, 0, stream>>>(vne, vnh);

    for (int l = 0; l < LL; l++) {
        k_aggr<<<Npad / 4, 256, 0, stream>>>(h, rowptr, einfo, comb + (size_t)l * 18 * DD,
                                             batch, vnh, (l > 0) ? 1 : 0, aggrb, N, Npad);
        k_gemm1<<<dim3(gx, 4), 256, 0, stream>>>(aggrb, w1t + (size_t)l * 640 * 320,
                                                 b1p + (size_t)l * 640, hidden);
        k_gemm2<<<dim3(gx, 2), 256, 0, stream>>>(hidden, w2t + (size_t)l * 320 * 640,
                                                 b2 + (size_t)l * DD,
                                                 bng + (size_t)l * DD, bnb + (size_t)l * DD,
                                                 bnm + (size_t)l * DD, bnv + (size_t)l * DD,
                                                 h, N, (l < LL - 1) ? 1 : 0);
        if (l < LL - 1) {
            k_pool2<<<GG, 256, 0, stream>>>(h, gptr, vnh, vnin);
            k_vng<<<dim3(GPAD / 64, 2), 256, 0, stream>>>(vnin, vw1t + (size_t)l * 320 * 320,
                                                          vb1 + (size_t)l * DD, tbuf, GG);
            k_ln<<<GG, 256, 0, stream>>>(tbuf, lng + (size_t)l * DD, lnb + (size_t)l * DD, vnrelu);
            k_vng<<<dim3(GPAD / 64, 2), 256, 0, stream>>>(vnrelu, vw2t + (size_t)l * 320 * 320,
                                                          vb2 + (size_t)l * DD, vnh, GG);
        }
    }
}